// Round 1
// baseline (321.840 us; speedup 1.0000x reference)
//
#include <hip/hip_runtime.h>
#include <hip/hip_bf16.h>
#include <math.h>
#include <stdint.h>

#define B_ 2
#define C_ 256
#define H_ 80
#define W_ 160
#define HW_ (H_*W_)      // 12800
#define NTOK (B_*HW_)    // 25600
#define G_ 8
#define P_ 8
#define NQKV 448         // 256 val + 128 off + 64 attn

typedef __bf16 bf16;
typedef __attribute__((ext_vector_type(8))) __bf16 bf16x8;
typedef __attribute__((ext_vector_type(4))) float f32x4;

__device__ __forceinline__ void gload_lds16(const void* g, void* l) {
  __builtin_amdgcn_global_load_lds(
      (__attribute__((address_space(1))) void*)g,
      (__attribute__((address_space(3))) void*)l,
      16, 0, 0);
}

// ---------------- weight prep: transpose to [N][K] bf16, concat qkv bias ----
__global__ __launch_bounds__(256)
void prep_weights(const float* __restrict__ vW, const float* __restrict__ vb,
                  const float* __restrict__ oW, const float* __restrict__ ob,
                  const float* __restrict__ aW, const float* __restrict__ ab,
                  const float* __restrict__ outW,
                  const float* __restrict__ w1, const float* __restrict__ w2,
                  bf16* __restrict__ wqkv, float* __restrict__ bqkv,
                  bf16* __restrict__ woutt, bf16* __restrict__ w1b, bf16* __restrict__ w2b)
{
  int i = blockIdx.x * 256 + threadIdx.x;
  if (i < NQKV*256) {                       // wqkv_t[n][k]
    int nn = i >> 8, k = i & 255;
    float w;
    if (nn < 256)      w = vW[k*256 + nn];
    else if (nn < 384) w = oW[k*128 + (nn-256)];
    else               w = aW[k*64  + (nn-384)];
    wqkv[i] = (bf16)w;
  }
  int j = i - NQKV*256;
  if (j >= 0 && j < 256*256) {              // outW_t[n][k]
    int nn = j >> 8, k = j & 255;
    woutt[j] = (bf16)outW[k*256 + nn];
  }
  int j2 = i - (NQKV*256 + 256*256);
  if (j2 >= 0 && j2 < 512*256) w1b[j2] = (bf16)w1[j2];   // already [N][K]
  int j3 = i - (NQKV*256 + 256*256 + 512*256);
  if (j3 >= 0 && j3 < 256*512) w2b[j3] = (bf16)w2[j3];   // already [N][K]
  int j4 = i - (NQKV*256 + 256*256 + 512*256 + 256*512);
  if (j4 >= 0 && j4 < NQKV) {
    float bv;
    if (j4 < 256)      bv = vb[j4];
    else if (j4 < 384) bv = ob[j4-256];
    else               bv = ab[j4-384];
    bqkv[j4] = bv;
  }
}

// ---------------- q = (feats+feats_pos) transposed NCHW -> (tok, C) ---------
__global__ __launch_bounds__(256)
void qprep_kernel(const float* __restrict__ f, const float* __restrict__ fp,
                  float* __restrict__ qf, bf16* __restrict__ qb)
{
  __shared__ float lt[64][65];
  const int tid = threadIdx.x;
  const int n0 = blockIdx.x * 64;   // token tile
  const int c0 = blockIdx.y * 64;   // channel tile
  const int b  = blockIdx.z;
#pragma unroll
  for (int i = 0; i < 16; ++i) {
    int cl = i*4 + (tid >> 6), nl = tid & 63;
    size_t gi = ((size_t)(b*C_ + c0 + cl))*HW_ + n0 + nl;
    lt[cl][nl] = f[gi] + fp[gi];
  }
  __syncthreads();
#pragma unroll
  for (int i = 0; i < 16; ++i) {
    int nl = i*4 + (tid >> 6), cl = tid & 63;
    float v = lt[cl][nl];
    size_t qi = ((size_t)(b*HW_ + n0 + nl))*C_ + c0 + cl;
    qf[qi] = v;
    qb[qi] = (bf16)v;
  }
}

// ---------------- generic bf16 MFMA GEMM: C[M x N] = A[M x K] * Bt[N x K]^T -
// EPI 0: qkv  -> val bf16 / off f32 / attn-logit f32 (bias = concat bias)
// EPI 1: out  -> x1 = acc + bias + res   (f32)
// EPI 2: ffn1 -> h = bf16(silu(acc+bias))
// EPI 3: ffn2 -> x2 = acc + bias + res   (f32)
template<int EPI, int KTOT>
__global__ __launch_bounds__(256, 2)
void gemm_kernel(const bf16* __restrict__ A, const bf16* __restrict__ Bt,
                 const float* __restrict__ bias,
                 void* __restrict__ out0, float* __restrict__ out1,
                 float* __restrict__ out2, const float* __restrict__ res)
{
  __shared__ bf16 lA[64*256];
  __shared__ bf16 lB[64*256];
  const int tid  = threadIdx.x;
  const int wave = tid >> 6, lane = tid & 63;
  const int m0 = blockIdx.x * 64, n0 = blockIdx.y * 64;
  const int wm = wave >> 1, wn = wave & 1;     // 2x2 wave grid, 32x32 each
  const int fr = lane & 15;
  const int fk = (lane >> 4) * 8;
  f32x4 acc[2][2] = {};

  for (int kc = 0; kc < KTOT/256; ++kc) {
    if (kc) __syncthreads();
#pragma unroll
    for (int it = 0; it < 8; ++it) {
      int e = it*2048 + tid*8;          // bf16 element index within 64x256 tile
      int row = e >> 8, kk = e & 255;
      gload_lds16(A  + (size_t)(m0+row)*KTOT + kc*256 + kk,
                  (char*)lA + it*4096 + wave*1024);
      gload_lds16(Bt + (size_t)(n0+row)*KTOT + kc*256 + kk,
                  (char*)lB + it*4096 + wave*1024);
    }
    __syncthreads();
#pragma unroll
    for (int ks = 0; ks < 8; ++ks) {
      bf16x8 a0 = *(const bf16x8*)&lA[(wm*32      + fr)*256 + ks*32 + fk];
      bf16x8 a1 = *(const bf16x8*)&lA[(wm*32 + 16 + fr)*256 + ks*32 + fk];
      bf16x8 b0 = *(const bf16x8*)&lB[(wn*32      + fr)*256 + ks*32 + fk];
      bf16x8 b1 = *(const bf16x8*)&lB[(wn*32 + 16 + fr)*256 + ks*32 + fk];
      acc[0][0] = __builtin_amdgcn_mfma_f32_16x16x32_bf16(a0, b0, acc[0][0], 0, 0, 0);
      acc[0][1] = __builtin_amdgcn_mfma_f32_16x16x32_bf16(a0, b1, acc[0][1], 0, 0, 0);
      acc[1][0] = __builtin_amdgcn_mfma_f32_16x16x32_bf16(a1, b0, acc[1][0], 0, 0, 0);
      acc[1][1] = __builtin_amdgcn_mfma_f32_16x16x32_bf16(a1, b1, acc[1][1], 0, 0, 0);
    }
  }

#pragma unroll
  for (int mi = 0; mi < 2; ++mi)
#pragma unroll
  for (int ni = 0; ni < 2; ++ni)
#pragma unroll
  for (int r = 0; r < 4; ++r) {
    int row = m0 + wm*32 + mi*16 + (lane >> 4)*4 + r;
    int col = n0 + wn*32 + ni*16 + fr;
    float v = acc[mi][ni][r] + bias[col];
    if (EPI == 0) {
      if (col < 256)      ((bf16*)out0)[(size_t)row*256 + col] = (bf16)v;
      else if (col < 384) out1[(size_t)row*128 + (col-256)] = v;
      else                out2[(size_t)row*64  + (col-384)] = v;
    } else if (EPI == 1) {
      ((float*)out0)[(size_t)row*256 + col] = v + res[(size_t)row*256 + col];
    } else if (EPI == 2) {
      float s = v / (1.0f + __expf(-v));
      ((bf16*)out0)[(size_t)row*512 + col] = (bf16)s;
    } else {
      ((float*)out0)[(size_t)row*256 + col] = v + res[(size_t)row*256 + col];
    }
  }
}

// ---------------- softmax + deformable bilinear sampling + aggregate --------
__global__ __launch_bounds__(256)
void sample_kernel(const bf16* __restrict__ val, const float* __restrict__ off,
                   const float* __restrict__ attnl, const float* __restrict__ anchors,
                   bf16* __restrict__ agg)
{
  const int tid = threadIdx.x;
  const int g = tid >> 5, cc = tid & 31;
  const int t = blockIdx.x;               // global token
  const int b = t / HW_;
  const float ax = anchors[(size_t)t*2 + 0] * W_ - 0.5f;
  const float ay = anchors[(size_t)t*2 + 1] * H_ - 0.5f;

  const float* lg = attnl + (size_t)t*64 + g*8;
  float l[8];
  float mx = -1e30f;
#pragma unroll
  for (int p = 0; p < 8; ++p) { l[p] = lg[p]; mx = fmaxf(mx, l[p]); }
  float s = 0.f;
#pragma unroll
  for (int p = 0; p < 8; ++p) { l[p] = __expf(l[p] - mx); s += l[p]; }
  const float inv = 1.f / s;

  const bf16* vb = val + (size_t)b*HW_*256 + g*32 + cc;
  const float* op = off + (size_t)t*128 + g*16;
  float a = 0.f;
#pragma unroll
  for (int p = 0; p < 8; ++p) {
    float px = ax + op[p*2 + 0];
    float py = ay + op[p*2 + 1];
    float x0f = floorf(px), y0f = floorf(py);
    int x0 = (int)x0f, y0 = (int)y0f;
    float wx1 = px - x0f, wx0 = 1.f - wx1;
    float wy1 = py - y0f, wy0 = 1.f - wy1;
    float sv = 0.f;
    if ((unsigned)x0     < W_ && (unsigned)y0     < H_) sv += wx0*wy0 * (float)vb[(size_t)(y0*W_ + x0    )*256];
    if ((unsigned)(x0+1) < W_ && (unsigned)y0     < H_) sv += wx1*wy0 * (float)vb[(size_t)(y0*W_ + x0 + 1)*256];
    if ((unsigned)x0     < W_ && (unsigned)(y0+1) < H_) sv += wx0*wy1 * (float)vb[(size_t)((y0+1)*W_ + x0    )*256];
    if ((unsigned)(x0+1) < W_ && (unsigned)(y0+1) < H_) sv += wx1*wy1 * (float)vb[(size_t)((y0+1)*W_ + x0 + 1)*256];
    a += (l[p] * inv) * sv;
  }
  agg[(size_t)t*256 + tid] = (bf16)a;
}

// ---------------- LayerNorm over C=256, one wave per token ------------------
__global__ __launch_bounds__(256)
void ln_kernel(const float* __restrict__ x, const float* __restrict__ gg,
               const float* __restrict__ bb, float* __restrict__ yf,
               bf16* __restrict__ yb)
{
  const int tid = threadIdx.x;
  const int wave = tid >> 6, lane = tid & 63;
  const size_t tok = (size_t)blockIdx.x*4 + wave;
  const float4 v = ((const float4*)(x + tok*256))[lane];
  float s = v.x + v.y + v.z + v.w;
  float q = v.x*v.x + v.y*v.y + v.z*v.z + v.w*v.w;
#pragma unroll
  for (int o = 32; o; o >>= 1) { s += __shfl_xor(s, o, 64); q += __shfl_xor(q, o, 64); }
  const float mean = s * (1.f/256.f);
  const float var  = q * (1.f/256.f) - mean*mean;
  const float rs   = rsqrtf(var + 1e-5f);
  const int c = lane*4;
  float o0 = (v.x - mean)*rs*gg[c+0] + bb[c+0];
  float o1 = (v.y - mean)*rs*gg[c+1] + bb[c+1];
  float o2 = (v.z - mean)*rs*gg[c+2] + bb[c+2];
  float o3 = (v.w - mean)*rs*gg[c+3] + bb[c+3];
  yf[tok*256 + c + 0] = o0; yf[tok*256 + c + 1] = o1;
  yf[tok*256 + c + 2] = o2; yf[tok*256 + c + 3] = o3;
  yb[tok*256 + c + 0] = (bf16)o0; yb[tok*256 + c + 1] = (bf16)o1;
  yb[tok*256 + c + 2] = (bf16)o2; yb[tok*256 + c + 3] = (bf16)o3;
}

// ---------------- LN2 + transpose back to (B, C, H, W) ----------------------
__global__ __launch_bounds__(256)
void ln2_out_kernel(const float* __restrict__ x, const float* __restrict__ gg,
                    const float* __restrict__ bb, float* __restrict__ out)
{
  __shared__ float lt[32][257];
  const int tid = threadIdx.x, wave = tid >> 6, lane = tid & 63;
  const int tok0 = blockIdx.x * 32;
#pragma unroll
  for (int t8 = 0; t8 < 8; ++t8) {
    const int tl = wave*8 + t8;
    const size_t tok = tok0 + tl;
    const float4 v = ((const float4*)(x + tok*256))[lane];
    float s = v.x + v.y + v.z + v.w;
    float q = v.x*v.x + v.y*v.y + v.z*v.z + v.w*v.w;
#pragma unroll
    for (int o = 32; o; o >>= 1) { s += __shfl_xor(s, o, 64); q += __shfl_xor(q, o, 64); }
    const float mean = s * (1.f/256.f);
    const float var  = q * (1.f/256.f) - mean*mean;
    const float rs   = rsqrtf(var + 1e-5f);
    const int c = lane*4;
    lt[tl][c+0] = (v.x - mean)*rs*gg[c+0] + bb[c+0];
    lt[tl][c+1] = (v.y - mean)*rs*gg[c+1] + bb[c+1];
    lt[tl][c+2] = (v.z - mean)*rs*gg[c+2] + bb[c+2];
    lt[tl][c+3] = (v.w - mean)*rs*gg[c+3] + bb[c+3];
  }
  __syncthreads();
  const int b  = tok0 / HW_;
  const int n0 = tok0 % HW_;
#pragma unroll
  for (int it = 0; it < 32; ++it) {
    int flat = it*256 + tid;
    int c = flat >> 5, tl = flat & 31;
    out[((size_t)(b*C_ + c))*HW_ + n0 + tl] = lt[tl][c];
  }
}

// ---------------- host-side orchestration -----------------------------------
extern "C" void kernel_launch(void* const* d_in, const int* in_sizes, int n_in,
                              void* d_out, int out_size, void* d_ws, size_t ws_size,
                              hipStream_t stream)
{
  const float* feats   = (const float*)d_in[0];
  const float* featsp  = (const float*)d_in[1];
  const float* anchors = (const float*)d_in[2];
  const float* value_W = (const float*)d_in[3];
  const float* value_b = (const float*)d_in[4];
  const float* off_W   = (const float*)d_in[5];
  const float* off_b   = (const float*)d_in[6];
  const float* attn_W  = (const float*)d_in[7];
  const float* attn_b  = (const float*)d_in[8];
  const float* out_W   = (const float*)d_in[9];
  const float* out_b   = (const float*)d_in[10];
  const float* ln1_g   = (const float*)d_in[11];
  const float* ln1_b   = (const float*)d_in[12];
  const float* ln2_g   = (const float*)d_in[13];
  const float* ln2_b   = (const float*)d_in[14];
  const float* w1      = (const float*)d_in[15];
  const float* b1      = (const float*)d_in[16];
  const float* w2      = (const float*)d_in[17];
  const float* b2      = (const float*)d_in[18];
  float* out = (float*)d_out;

  char* ws = (char*)d_ws;
  size_t cur = 0;
  auto alloc = [&](size_t bytes) -> char* {
    char* p = ws + cur;
    cur += (bytes + 255) & ~(size_t)255;
    return p;
  };
  bf16*  wqkv  = (bf16*) alloc((size_t)NQKV*256*2);
  bf16*  woutt = (bf16*) alloc((size_t)256*256*2);
  bf16*  w1b   = (bf16*) alloc((size_t)512*256*2);
  bf16*  w2b   = (bf16*) alloc((size_t)256*512*2);
  float* bqkv  = (float*)alloc((size_t)NQKV*4);
  float* qf    = (float*)alloc((size_t)NTOK*256*4);   // reused as x2
  bf16*  qb    = (bf16*) alloc((size_t)NTOK*256*2);   // reused as agg
  bf16*  valb  = (bf16*) alloc((size_t)NTOK*256*2);   // x1 overlays valb+offv
  float* offv  = (float*)alloc((size_t)NTOK*128*4);
  float* attnl = (float*)alloc((size_t)NTOK*64*4);
  float* y1f   = (float*)alloc((size_t)NTOK*256*4);
  bf16*  y1b   = (bf16*) alloc((size_t)NTOK*256*2);
  bf16*  hb    = (bf16*) alloc((size_t)NTOK*512*2);
  float* x1   = (float*)valb;   // 26.2 MB overlay (valb+offv dead after sampling)
  float* x2   = qf;             // q dead after gemm<1> epilogue
  bf16*  aggb = qb;             // q_bf16 dead after gemm<0>

  prep_weights<<<(NQKV*256 + 256*256 + 512*256 + 256*512 + NQKV + 255)/256, 256, 0, stream>>>(
      value_W, value_b, off_W, off_b, attn_W, attn_b, out_W, w1, w2,
      wqkv, bqkv, woutt, w1b, w2b);

  qprep_kernel<<<dim3(HW_/64, C_/64, B_), 256, 0, stream>>>(feats, featsp, qf, qb);

  gemm_kernel<0, 256><<<dim3(NTOK/64, NQKV/64), 256, 0, stream>>>(
      qb, wqkv, bqkv, valb, offv, attnl, nullptr);

  sample_kernel<<<NTOK, 256, 0, stream>>>(valb, offv, attnl, anchors, aggb);

  gemm_kernel<1, 256><<<dim3(NTOK/64, 256/64), 256, 0, stream>>>(
      aggb, woutt, out_b, x1, nullptr, nullptr, qf);

  ln_kernel<<<NTOK/4, 256, 0, stream>>>(x1, ln1_g, ln1_b, y1f, y1b);

  gemm_kernel<2, 256><<<dim3(NTOK/64, 512/64), 256, 0, stream>>>(
      y1b, w1b, b1, hb, nullptr, nullptr, nullptr);

  gemm_kernel<3, 512><<<dim3(NTOK/64, 256/64), 256, 0, stream>>>(
      hb, w2b, b2, x2, nullptr, nullptr, y1f);

  ln2_out_kernel<<<NTOK/32, 256, 0, stream>>>(x2, ln2_g, ln2_b, out);
}

// Round 2
// 204.707 us; speedup vs baseline: 1.5722x; 1.5722x over previous
//
#include <hip/hip_runtime.h>
#include <hip/hip_bf16.h>
#include <math.h>
#include <stdint.h>

#define B_ 2
#define C_ 256
#define H_ 80
#define W_ 160
#define HW_ (H_*W_)      // 12800
#define NTOK (B_*HW_)    // 25600
#define G_ 8
#define P_ 8
#define NQKV 448         // 256 val + 128 off + 64 attn

typedef __bf16 bf16;
typedef __attribute__((ext_vector_type(8))) __bf16 bf16x8;
typedef __attribute__((ext_vector_type(4))) float f32x4;

__device__ __forceinline__ void gload_lds16(const void* g, void* l) {
  __builtin_amdgcn_global_load_lds(
      (__attribute__((address_space(1))) void*)g,
      (__attribute__((address_space(3))) void*)l,
      16, 0, 0);
}

// ---------------- weight prep: transpose to [N][K] bf16, concat qkv bias ----
__global__ __launch_bounds__(256)
void prep_weights(const float* __restrict__ vW, const float* __restrict__ vb,
                  const float* __restrict__ oW, const float* __restrict__ ob,
                  const float* __restrict__ aW, const float* __restrict__ ab,
                  const float* __restrict__ outW,
                  const float* __restrict__ w1, const float* __restrict__ w2,
                  bf16* __restrict__ wqkv, float* __restrict__ bqkv,
                  bf16* __restrict__ woutt, bf16* __restrict__ w1b, bf16* __restrict__ w2b)
{
  int i = blockIdx.x * 256 + threadIdx.x;
  if (i < NQKV*256) {                       // wqkv_t[n][k]
    int nn = i >> 8, k = i & 255;
    float w;
    if (nn < 256)      w = vW[k*256 + nn];
    else if (nn < 384) w = oW[k*128 + (nn-256)];
    else               w = aW[k*64  + (nn-384)];
    wqkv[i] = (bf16)w;
  }
  int j = i - NQKV*256;
  if (j >= 0 && j < 256*256) {              // outW_t[n][k]
    int nn = j >> 8, k = j & 255;
    woutt[j] = (bf16)outW[k*256 + nn];
  }
  int j2 = i - (NQKV*256 + 256*256);
  if (j2 >= 0 && j2 < 512*256) w1b[j2] = (bf16)w1[j2];   // already [N][K]
  int j3 = i - (NQKV*256 + 256*256 + 512*256);
  if (j3 >= 0 && j3 < 256*512) w2b[j3] = (bf16)w2[j3];   // already [N][K]
  int j4 = i - (NQKV*256 + 256*256 + 512*256 + 256*512);
  if (j4 >= 0 && j4 < NQKV) {
    float bv;
    if (j4 < 256)      bv = vb[j4];
    else if (j4 < 384) bv = ob[j4-256];
    else               bv = ab[j4-384];
    bqkv[j4] = bv;
  }
}

// ---------------- q = (feats+feats_pos) transposed NCHW -> (tok, C) ---------
__global__ __launch_bounds__(256)
void qprep_kernel(const float* __restrict__ f, const float* __restrict__ fp,
                  float* __restrict__ qf, bf16* __restrict__ qb)
{
  __shared__ float lt[64][65];
  const int tid = threadIdx.x;
  const int n0 = blockIdx.x * 64;   // token tile
  const int c0 = blockIdx.y * 64;   // channel tile
  const int b  = blockIdx.z;
#pragma unroll
  for (int i = 0; i < 16; ++i) {
    int cl = i*4 + (tid >> 6), nl = tid & 63;
    size_t gi = ((size_t)(b*C_ + c0 + cl))*HW_ + n0 + nl;
    lt[cl][nl] = f[gi] + fp[gi];
  }
  __syncthreads();
#pragma unroll
  for (int i = 0; i < 16; ++i) {
    int nl = i*4 + (tid >> 6), cl = tid & 63;
    float v = lt[cl][nl];
    size_t qi = ((size_t)(b*HW_ + n0 + nl))*C_ + c0 + cl;
    qf[qi] = v;
    qb[qi] = (bf16)v;
  }
}

// ---------------- generic bf16 MFMA GEMM: C[M x N] = A[M x K] * Bt[N x K]^T -
// EPI 0: qkv  -> val bf16 / off f32 / attn-logit f32 (bias = concat bias)
// EPI 1: out  -> x1 = acc + bias + res   (f32)
// EPI 2: ffn1 -> h = bf16(silu(acc+bias))
// EPI 3: ffn2 -> x2 = acc + bias + res   (f32)
template<int EPI, int KTOT>
__global__ __launch_bounds__(256, 2)
void gemm_kernel(const bf16* __restrict__ A, const bf16* __restrict__ Bt,
                 const float* __restrict__ bias,
                 void* __restrict__ out0, float* __restrict__ out1,
                 float* __restrict__ out2, const float* __restrict__ res)
{
  __shared__ bf16 lA[64*256];
  __shared__ bf16 lB[64*256];
  const int tid  = threadIdx.x;
  const int wave = tid >> 6, lane = tid & 63;
  const int m0 = blockIdx.x * 64, n0 = blockIdx.y * 64;
  const int wm = wave >> 1, wn = wave & 1;     // 2x2 wave grid, 32x32 each
  const int fr = lane & 15;
  const int fk = (lane >> 4) * 8;
  f32x4 acc[2][2] = {};

  for (int kc = 0; kc < KTOT/256; ++kc) {
    if (kc) __syncthreads();
#pragma unroll
    for (int it = 0; it < 8; ++it) {
      int e = it*2048 + tid*8;          // bf16 element index within 64x256 tile
      int row = e >> 8, kk = e & 255;
      gload_lds16(A  + (size_t)(m0+row)*KTOT + kc*256 + kk,
                  (char*)lA + it*4096 + wave*1024);
      gload_lds16(Bt + (size_t)(n0+row)*KTOT + kc*256 + kk,
                  (char*)lB + it*4096 + wave*1024);
    }
    __syncthreads();
#pragma unroll
    for (int ks = 0; ks < 8; ++ks) {
      bf16x8 a0 = *(const bf16x8*)&lA[(wm*32      + fr)*256 + ks*32 + fk];
      bf16x8 a1 = *(const bf16x8*)&lA[(wm*32 + 16 + fr)*256 + ks*32 + fk];
      bf16x8 b0 = *(const bf16x8*)&lB[(wn*32      + fr)*256 + ks*32 + fk];
      bf16x8 b1 = *(const bf16x8*)&lB[(wn*32 + 16 + fr)*256 + ks*32 + fk];
      acc[0][0] = __builtin_amdgcn_mfma_f32_16x16x32_bf16(a0, b0, acc[0][0], 0, 0, 0);
      acc[0][1] = __builtin_amdgcn_mfma_f32_16x16x32_bf16(a0, b1, acc[0][1], 0, 0, 0);
      acc[1][0] = __builtin_amdgcn_mfma_f32_16x16x32_bf16(a1, b0, acc[1][0], 0, 0, 0);
      acc[1][1] = __builtin_amdgcn_mfma_f32_16x16x32_bf16(a1, b1, acc[1][1], 0, 0, 0);
    }
  }

#pragma unroll
  for (int mi = 0; mi < 2; ++mi)
#pragma unroll
  for (int ni = 0; ni < 2; ++ni)
#pragma unroll
  for (int r = 0; r < 4; ++r) {
    int row = m0 + wm*32 + mi*16 + (lane >> 4)*4 + r;
    int col = n0 + wn*32 + ni*16 + fr;
    float v = acc[mi][ni][r] + bias[col];
    if (EPI == 0) {
      if (col < 256)      ((bf16*)out0)[(size_t)row*256 + col] = (bf16)v;
      else if (col < 384) out1[(size_t)row*128 + (col-256)] = v;
      else                out2[(size_t)row*64  + (col-384)] = v;
    } else if (EPI == 1) {
      ((float*)out0)[(size_t)row*256 + col] = v + res[(size_t)row*256 + col];
    } else if (EPI == 2) {
      float s = v / (1.0f + __expf(-v));
      ((bf16*)out0)[(size_t)row*512 + col] = (bf16)s;
    } else {
      ((float*)out0)[(size_t)row*256 + col] = v + res[(size_t)row*256 + col];
    }
  }
}

// ---------------- softmax + deformable bilinear sampling + aggregate --------
// Lane map: lane = (tsub:1)(g:3)(c8:2) -> one wave = 2 tokens, 8 groups,
// 4 lanes/group each owning 8 channels via 16B bf16x8 gathers.
__global__ __launch_bounds__(256)
void sample_kernel(const bf16* __restrict__ val, const float* __restrict__ off,
                   const float* __restrict__ attnl, const float* __restrict__ anchors,
                   bf16* __restrict__ agg)
{
  const int tid  = threadIdx.x;
  const int lane = tid & 63;
  const int wv   = tid >> 6;
  const int tsub = lane >> 5;
  const int g    = (lane >> 2) & 7;
  const int c8   = lane & 3;
  const int t    = blockIdx.x * 8 + wv * 2 + tsub;
  const int b    = t / HW_;

  const float2 anc = *(const float2*)(anchors + (size_t)t*2);
  const float ax = anc.x * W_ - 0.5f;
  const float ay = anc.y * H_ - 0.5f;

  // softmax over this group's 8 point logits (replicated across 4 lanes; cached)
  const float4 l0 = *(const float4*)(attnl + (size_t)t*64 + g*8);
  const float4 l1 = *(const float4*)(attnl + (size_t)t*64 + g*8 + 4);
  float l[8] = {l0.x, l0.y, l0.z, l0.w, l1.x, l1.y, l1.z, l1.w};
  float mx = l[0];
#pragma unroll
  for (int p = 1; p < 8; ++p) mx = fmaxf(mx, l[p]);
  float s = 0.f;
#pragma unroll
  for (int p = 0; p < 8; ++p) { l[p] = __expf(l[p] - mx); s += l[p]; }
  const float inv = 1.f / s;

  // the group's 8 offset pairs (16 floats) up front
  const float4* opv = (const float4*)(off + (size_t)t*128 + g*16);
  const float4 o0 = opv[0], o1 = opv[1], o2 = opv[2], o3 = opv[3];
  const float ox[8] = {o0.x, o0.z, o1.x, o1.z, o2.x, o2.z, o3.x, o3.z};
  const float oy[8] = {o0.y, o0.w, o1.y, o1.w, o2.y, o2.w, o3.y, o3.w};

  const bf16* vb = val + ((size_t)b*HW_)*256 + g*32 + c8*8;

  float a[8] = {};
#pragma unroll
  for (int p = 0; p < 8; ++p) {
    const float px = ax + ox[p], py = ay + oy[p];
    const float x0f = floorf(px), y0f = floorf(py);
    const int x0 = (int)x0f, y0 = (int)y0f;
    const float wx1 = px - x0f, wx0 = 1.f - wx1;
    const float wy1 = py - y0f, wy0 = 1.f - wy1;
    const float ap = l[p] * inv;
    float w00 = ap*wx0*wy0, w10 = ap*wx1*wy0, w01 = ap*wx0*wy1, w11 = ap*wx1*wy1;
    const bool vx0 = (unsigned)x0 < W_, vx1 = (unsigned)(x0+1) < W_;
    const bool vy0 = (unsigned)y0 < H_, vy1 = (unsigned)(y0+1) < H_;
    w00 = (vx0 && vy0) ? w00 : 0.f;  w10 = (vx1 && vy0) ? w10 : 0.f;
    w01 = (vx0 && vy1) ? w01 : 0.f;  w11 = (vx1 && vy1) ? w11 : 0.f;
    const int xc0 = min(max(x0, 0), W_-1),   xc1 = min(max(x0+1, 0), W_-1);
    const int yc0 = min(max(y0, 0), H_-1),   yc1 = min(max(y0+1, 0), H_-1);
    const bf16x8 v00 = *(const bf16x8*)(vb + (size_t)(yc0*W_ + xc0)*256);
    const bf16x8 v10 = *(const bf16x8*)(vb + (size_t)(yc0*W_ + xc1)*256);
    const bf16x8 v01 = *(const bf16x8*)(vb + (size_t)(yc1*W_ + xc0)*256);
    const bf16x8 v11 = *(const bf16x8*)(vb + (size_t)(yc1*W_ + xc1)*256);
#pragma unroll
    for (int c = 0; c < 8; ++c)
      a[c] += w00*(float)v00[c] + w10*(float)v10[c]
            + w01*(float)v01[c] + w11*(float)v11[c];
  }
  bf16 r[8];
#pragma unroll
  for (int c = 0; c < 8; ++c) r[c] = (bf16)a[c];
  *(bf16x8*)(agg + (size_t)t*256 + g*32 + c8*8) = *(bf16x8*)r;
}

// ---------------- LayerNorm over C=256, one wave per token ------------------
__global__ __launch_bounds__(256)
void ln_kernel(const float* __restrict__ x, const float* __restrict__ gg,
               const float* __restrict__ bb, float* __restrict__ yf,
               bf16* __restrict__ yb)
{
  const int tid = threadIdx.x;
  const int wave = tid >> 6, lane = tid & 63;
  const size_t tok = (size_t)blockIdx.x*4 + wave;
  const float4 v = ((const float4*)(x + tok*256))[lane];
  float s = v.x + v.y + v.z + v.w;
  float q = v.x*v.x + v.y*v.y + v.z*v.z + v.w*v.w;
#pragma unroll
  for (int o = 32; o; o >>= 1) { s += __shfl_xor(s, o, 64); q += __shfl_xor(q, o, 64); }
  const float mean = s * (1.f/256.f);
  const float var  = q * (1.f/256.f) - mean*mean;
  const float rs   = rsqrtf(var + 1e-5f);
  const int c = lane*4;
  float o0 = (v.x - mean)*rs*gg[c+0] + bb[c+0];
  float o1 = (v.y - mean)*rs*gg[c+1] + bb[c+1];
  float o2 = (v.z - mean)*rs*gg[c+2] + bb[c+2];
  float o3 = (v.w - mean)*rs*gg[c+3] + bb[c+3];
  yf[tok*256 + c + 0] = o0; yf[tok*256 + c + 1] = o1;
  yf[tok*256 + c + 2] = o2; yf[tok*256 + c + 3] = o3;
  yb[tok*256 + c + 0] = (bf16)o0; yb[tok*256 + c + 1] = (bf16)o1;
  yb[tok*256 + c + 2] = (bf16)o2; yb[tok*256 + c + 3] = (bf16)o3;
}

// ---------------- LN2 + transpose back to (B, C, H, W) ----------------------
__global__ __launch_bounds__(256)
void ln2_out_kernel(const float* __restrict__ x, const float* __restrict__ gg,
                    const float* __restrict__ bb, float* __restrict__ out)
{
  __shared__ float lt[32][257];
  const int tid = threadIdx.x, wave = tid >> 6, lane = tid & 63;
  const int tok0 = blockIdx.x * 32;
#pragma unroll
  for (int t8 = 0; t8 < 8; ++t8) {
    const int tl = wave*8 + t8;
    const size_t tok = tok0 + tl;
    const float4 v = ((const float4*)(x + tok*256))[lane];
    float s = v.x + v.y + v.z + v.w;
    float q = v.x*v.x + v.y*v.y + v.z*v.z + v.w*v.w;
#pragma unroll
    for (int o = 32; o; o >>= 1) { s += __shfl_xor(s, o, 64); q += __shfl_xor(q, o, 64); }
    const float mean = s * (1.f/256.f);
    const float var  = q * (1.f/256.f) - mean*mean;
    const float rs   = rsqrtf(var + 1e-5f);
    const int c = lane*4;
    lt[tl][c+0] = (v.x - mean)*rs*gg[c+0] + bb[c+0];
    lt[tl][c+1] = (v.y - mean)*rs*gg[c+1] + bb[c+1];
    lt[tl][c+2] = (v.z - mean)*rs*gg[c+2] + bb[c+2];
    lt[tl][c+3] = (v.w - mean)*rs*gg[c+3] + bb[c+3];
  }
  __syncthreads();
  const int b  = tok0 / HW_;
  const int n0 = tok0 % HW_;
#pragma unroll
  for (int it = 0; it < 32; ++it) {
    int flat = it*256 + tid;
    int c = flat >> 5, tl = flat & 31;
    out[((size_t)(b*C_ + c))*HW_ + n0 + tl] = lt[tl][c];
  }
}

// ---------------- host-side orchestration -----------------------------------
extern "C" void kernel_launch(void* const* d_in, const int* in_sizes, int n_in,
                              void* d_out, int out_size, void* d_ws, size_t ws_size,
                              hipStream_t stream)
{
  const float* feats   = (const float*)d_in[0];
  const float* featsp  = (const float*)d_in[1];
  const float* anchors = (const float*)d_in[2];
  const float* value_W = (const float*)d_in[3];
  const float* value_b = (const float*)d_in[4];
  const float* off_W   = (const float*)d_in[5];
  const float* off_b   = (const float*)d_in[6];
  const float* attn_W  = (const float*)d_in[7];
  const float* attn_b  = (const float*)d_in[8];
  const float* out_W   = (const float*)d_in[9];
  const float* out_b   = (const float*)d_in[10];
  const float* ln1_g   = (const float*)d_in[11];
  const float* ln1_b   = (const float*)d_in[12];
  const float* ln2_g   = (const float*)d_in[13];
  const float* ln2_b   = (const float*)d_in[14];
  const float* w1      = (const float*)d_in[15];
  const float* b1      = (const float*)d_in[16];
  const float* w2      = (const float*)d_in[17];
  const float* b2      = (const float*)d_in[18];
  float* out = (float*)d_out;

  char* ws = (char*)d_ws;
  size_t cur = 0;
  auto alloc = [&](size_t bytes) -> char* {
    char* p = ws + cur;
    cur += (bytes + 255) & ~(size_t)255;
    return p;
  };
  bf16*  wqkv  = (bf16*) alloc((size_t)NQKV*256*2);
  bf16*  woutt = (bf16*) alloc((size_t)256*256*2);
  bf16*  w1b   = (bf16*) alloc((size_t)512*256*2);
  bf16*  w2b   = (bf16*) alloc((size_t)256*512*2);
  float* bqkv  = (float*)alloc((size_t)NQKV*4);
  float* qf    = (float*)alloc((size_t)NTOK*256*4);   // reused as x2
  bf16*  qb    = (bf16*) alloc((size_t)NTOK*256*2);   // reused as agg
  bf16*  valb  = (bf16*) alloc((size_t)NTOK*256*2);   // x1 overlays valb+offv
  float* offv  = (float*)alloc((size_t)NTOK*128*4);
  float* attnl = (float*)alloc((size_t)NTOK*64*4);
  float* y1f   = (float*)alloc((size_t)NTOK*256*4);
  bf16*  y1b   = (bf16*) alloc((size_t)NTOK*256*2);
  bf16*  hb    = (bf16*) alloc((size_t)NTOK*512*2);
  float* x1   = (float*)valb;   // 26.2 MB overlay (valb+offv dead after sampling)
  float* x2   = qf;             // q dead after gemm<1> epilogue
  bf16*  aggb = qb;             // q_bf16 dead after gemm<0>

  prep_weights<<<(NQKV*256 + 256*256 + 512*256 + 256*512 + NQKV + 255)/256, 256, 0, stream>>>(
      value_W, value_b, off_W, off_b, attn_W, attn_b, out_W, w1, w2,
      wqkv, bqkv, woutt, w1b, w2b);

  qprep_kernel<<<dim3(HW_/64, C_/64, B_), 256, 0, stream>>>(feats, featsp, qf, qb);

  gemm_kernel<0, 256><<<dim3(NTOK/64, NQKV/64), 256, 0, stream>>>(
      qb, wqkv, bqkv, valb, offv, attnl, nullptr);

  sample_kernel<<<NTOK/8, 256, 0, stream>>>(valb, offv, attnl, anchors, aggb);

  gemm_kernel<1, 256><<<dim3(NTOK/64, 256/64), 256, 0, stream>>>(
      aggb, woutt, out_b, x1, nullptr, nullptr, qf);

  ln_kernel<<<NTOK/4, 256, 0, stream>>>(x1, ln1_g, ln1_b, y1f, y1b);

  gemm_kernel<2, 256><<<dim3(NTOK/64, 512/64), 256, 0, stream>>>(
      y1b, w1b, b1, hb, nullptr, nullptr, nullptr);

  gemm_kernel<3, 512><<<dim3(NTOK/64, 256/64), 256, 0, stream>>>(
      hb, w2b, b2, x2, nullptr, nullptr, y1f);

  ln2_out_kernel<<<NTOK/32, 256, 0, stream>>>(x2, ln2_g, ln2_b, out);
}

// Round 3
// 177.795 us; speedup vs baseline: 1.8102x; 1.1514x over previous
//
#include <hip/hip_runtime.h>
#include <hip/hip_bf16.h>
#include <math.h>
#include <stdint.h>

#define B_ 2
#define C_ 256
#define H_ 80
#define W_ 160
#define HW_ (H_*W_)      // 12800
#define NTOK (B_*HW_)    // 25600
#define G_ 8
#define P_ 8
#define NQKV 448         // 256 val + 128 off + 64 attn (padded to 512 for tiles)
#define NQKVP 512

typedef __bf16 bf16;
typedef __attribute__((ext_vector_type(8))) __bf16 bf16x8;
typedef __attribute__((ext_vector_type(4))) float f32x4;

__device__ __forceinline__ void gload_lds16(const void* g, void* l) {
  __builtin_amdgcn_global_load_lds(
      (__attribute__((address_space(1))) void*)g,
      (__attribute__((address_space(3))) void*)l,
      16, 0, 0);
}

// ---------------- weight prep: transpose to [N][K] bf16, concat+pad qkv -----
__global__ __launch_bounds__(256)
void prep_weights(const float* __restrict__ vW, const float* __restrict__ vb,
                  const float* __restrict__ oW, const float* __restrict__ ob,
                  const float* __restrict__ aW, const float* __restrict__ ab,
                  const float* __restrict__ outW,
                  const float* __restrict__ w1, const float* __restrict__ w2,
                  bf16* __restrict__ wqkv, float* __restrict__ bqkv,
                  bf16* __restrict__ woutt, bf16* __restrict__ w1b, bf16* __restrict__ w2b)
{
  int i = blockIdx.x * 256 + threadIdx.x;
  if (i < NQKVP*256) {                      // wqkv_t[n][k], zero-padded rows
    int nn = i >> 8, k = i & 255;
    float w;
    if (nn < 256)      w = vW[k*256 + nn];
    else if (nn < 384) w = oW[k*128 + (nn-256)];
    else if (nn < 448) w = aW[k*64  + (nn-384)];
    else               w = 0.f;
    wqkv[i] = (bf16)w;
  }
  int j = i - NQKVP*256;
  if (j >= 0 && j < 256*256) {              // outW_t[n][k]
    int nn = j >> 8, k = j & 255;
    woutt[j] = (bf16)outW[k*256 + nn];
  }
  int j2 = i - (NQKVP*256 + 256*256);
  if (j2 >= 0 && j2 < 512*256) w1b[j2] = (bf16)w1[j2];   // already [N][K]
  int j3 = i - (NQKVP*256 + 256*256 + 512*256);
  if (j3 >= 0 && j3 < 256*512) w2b[j3] = (bf16)w2[j3];   // already [N][K]
  int j4 = i - (NQKVP*256 + 256*256 + 512*256 + 256*512);
  if (j4 >= 0 && j4 < NQKVP) {
    float bv;
    if (j4 < 256)      bv = vb[j4];
    else if (j4 < 384) bv = ob[j4-256];
    else if (j4 < 448) bv = ab[j4-384];
    else               bv = 0.f;
    bqkv[j4] = bv;
  }
}

// ---------------- q = (feats+feats_pos) transposed NCHW -> (tok, C) ---------
__global__ __launch_bounds__(256)
void qprep_kernel(const float* __restrict__ f, const float* __restrict__ fp,
                  float* __restrict__ qf, bf16* __restrict__ qb)
{
  __shared__ float lt[64][65];
  const int tid = threadIdx.x;
  const int n0 = blockIdx.x * 64;   // token tile
  const int c0 = blockIdx.y * 64;   // channel tile
  const int b  = blockIdx.z;
#pragma unroll
  for (int i = 0; i < 16; ++i) {
    int cl = i*4 + (tid >> 6), nl = tid & 63;
    size_t gi = ((size_t)(b*C_ + c0 + cl))*HW_ + n0 + nl;
    lt[cl][nl] = f[gi] + fp[gi];
  }
  __syncthreads();
#pragma unroll
  for (int i = 0; i < 16; ++i) {
    int nl = i*4 + (tid >> 6), cl = tid & 63;
    float v = lt[cl][nl];
    size_t qi = ((size_t)(b*HW_ + n0 + nl))*C_ + c0 + cl;
    qf[qi] = v;
    qb[qi] = (bf16)v;
  }
}

// ---------------- bf16 MFMA GEMM, 128x128 tile, BK=64, XOR-swizzled LDS -----
// C[M x N] = A[M x K] * Bt[N x K]^T  (m97-style structure)
// EPI 0: qkv  -> val bf16 / off f32 / attn-logit f32 (cols >= 448 dropped)
// EPI 1: out  -> x1 = acc + bias + res   (f32)
// EPI 2: ffn1 -> h = bf16(silu(acc+bias))
// EPI 3: ffn2 -> x2 = acc + bias + res   (f32)
template<int EPI, int KTOT>
__global__ __launch_bounds__(256)
void gemm_kernel(const bf16* __restrict__ A, const bf16* __restrict__ Bt,
                 const float* __restrict__ bias,
                 void* __restrict__ out0, float* __restrict__ out1,
                 float* __restrict__ out2, const float* __restrict__ res)
{
  __shared__ bf16 lA[128*64];   // 16 KB, [row][BK] with chunk-XOR swizzle
  __shared__ bf16 lB[128*64];   // 16 KB
  const int tid  = threadIdx.x;
  const int wave = tid >> 6, lane = tid & 63;
  const int m0 = blockIdx.x * 128, n0 = blockIdx.y * 128;
  const int wm = wave >> 1, wn = wave & 1;     // 2x2 wave grid, 64x64 each
  const int fr = lane & 15;
  const int fq = lane >> 4;
  f32x4 acc[4][4] = {};

  for (int kc = 0; kc < KTOT/64; ++kc) {
    if (kc) __syncthreads();
    // stage A,B tiles: linear LDS dest, XOR-pre-swizzled global source (rule 21)
#pragma unroll
    for (int it = 0; it < 4; ++it) {
      int chunk = it*256 + tid;          // 16B-chunk index in 128x64 tile
      int row = chunk >> 3, cb = chunk & 7;
      int ksw = ((cb ^ (row & 7)) << 3); // swizzled k-element offset
      gload_lds16(A  + (size_t)(m0+row)*KTOT + kc*64 + ksw,
                  (char*)lA + it*4096 + wave*1024);
      gload_lds16(Bt + (size_t)(n0+row)*KTOT + kc*64 + ksw,
                  (char*)lB + it*4096 + wave*1024);
    }
    __syncthreads();
#pragma unroll
    for (int ks = 0; ks < 2; ++ks) {
      bf16x8 af[4], bg[4];
#pragma unroll
      for (int i = 0; i < 4; ++i) {
        int ar = wm*64 + i*16 + fr;
        af[i] = *(const bf16x8*)&lA[ar*64 + (((ks*4 + fq) ^ (ar & 7)) << 3)];
        int br = wn*64 + i*16 + fr;
        bg[i] = *(const bf16x8*)&lB[br*64 + (((ks*4 + fq) ^ (br & 7)) << 3)];
      }
#pragma unroll
      for (int mi = 0; mi < 4; ++mi)
#pragma unroll
        for (int ni = 0; ni < 4; ++ni)
          acc[mi][ni] = __builtin_amdgcn_mfma_f32_16x16x32_bf16(af[mi], bg[ni], acc[mi][ni], 0, 0, 0);
    }
  }

#pragma unroll
  for (int mi = 0; mi < 4; ++mi)
#pragma unroll
  for (int ni = 0; ni < 4; ++ni)
#pragma unroll
  for (int r = 0; r < 4; ++r) {
    int row = m0 + wm*64 + mi*16 + fq*4 + r;
    int col = n0 + wn*64 + ni*16 + fr;
    float v = acc[mi][ni][r] + bias[col];
    if (EPI == 0) {
      if (col < 256)      ((bf16*)out0)[(size_t)row*256 + col] = (bf16)v;
      else if (col < 384) out1[(size_t)row*128 + (col-256)] = v;
      else if (col < 448) out2[(size_t)row*64  + (col-384)] = v;
      // cols 448..511 are padding: dropped
    } else if (EPI == 1) {
      ((float*)out0)[(size_t)row*256 + col] = v + res[(size_t)row*256 + col];
    } else if (EPI == 2) {
      float s = v / (1.0f + __expf(-v));
      ((bf16*)out0)[(size_t)row*512 + col] = (bf16)s;
    } else {
      ((float*)out0)[(size_t)row*256 + col] = v + res[(size_t)row*256 + col];
    }
  }
}

// ---------------- softmax + deformable bilinear sampling + aggregate --------
// Lane map: lane = (tsub:1)(g:3)(c8:2) -> one wave = 2 tokens, 8 groups,
// 4 lanes/group each owning 8 channels via 16B bf16x8 gathers.
__global__ __launch_bounds__(256)
void sample_kernel(const bf16* __restrict__ val, const float* __restrict__ off,
                   const float* __restrict__ attnl, const float* __restrict__ anchors,
                   bf16* __restrict__ agg)
{
  const int tid  = threadIdx.x;
  const int lane = tid & 63;
  const int wv   = tid >> 6;
  const int tsub = lane >> 5;
  const int g    = (lane >> 2) & 7;
  const int c8   = lane & 3;
  const int t    = blockIdx.x * 8 + wv * 2 + tsub;
  const int b    = t / HW_;

  const float2 anc = *(const float2*)(anchors + (size_t)t*2);
  const float ax = anc.x * W_ - 0.5f;
  const float ay = anc.y * H_ - 0.5f;

  const float4 l0 = *(const float4*)(attnl + (size_t)t*64 + g*8);
  const float4 l1 = *(const float4*)(attnl + (size_t)t*64 + g*8 + 4);
  float l[8] = {l0.x, l0.y, l0.z, l0.w, l1.x, l1.y, l1.z, l1.w};
  float mx = l[0];
#pragma unroll
  for (int p = 1; p < 8; ++p) mx = fmaxf(mx, l[p]);
  float s = 0.f;
#pragma unroll
  for (int p = 0; p < 8; ++p) { l[p] = __expf(l[p] - mx); s += l[p]; }
  const float inv = 1.f / s;

  const float4* opv = (const float4*)(off + (size_t)t*128 + g*16);
  const float4 o0 = opv[0], o1 = opv[1], o2 = opv[2], o3 = opv[3];
  const float ox[8] = {o0.x, o0.z, o1.x, o1.z, o2.x, o2.z, o3.x, o3.z};
  const float oy[8] = {o0.y, o0.w, o1.y, o1.w, o2.y, o2.w, o3.y, o3.w};

  const bf16* vb = val + ((size_t)b*HW_)*256 + g*32 + c8*8;

  float a[8] = {};
#pragma unroll
  for (int p = 0; p < 8; ++p) {
    const float px = ax + ox[p], py = ay + oy[p];
    const float x0f = floorf(px), y0f = floorf(py);
    const int x0 = (int)x0f, y0 = (int)y0f;
    const float wx1 = px - x0f, wx0 = 1.f - wx1;
    const float wy1 = py - y0f, wy0 = 1.f - wy1;
    const float ap = l[p] * inv;
    float w00 = ap*wx0*wy0, w10 = ap*wx1*wy0, w01 = ap*wx0*wy1, w11 = ap*wx1*wy1;
    const bool vx0 = (unsigned)x0 < W_, vx1 = (unsigned)(x0+1) < W_;
    const bool vy0 = (unsigned)y0 < H_, vy1 = (unsigned)(y0+1) < H_;
    w00 = (vx0 && vy0) ? w00 : 0.f;  w10 = (vx1 && vy0) ? w10 : 0.f;
    w01 = (vx0 && vy1) ? w01 : 0.f;  w11 = (vx1 && vy1) ? w11 : 0.f;
    const int xc0 = min(max(x0, 0), W_-1),   xc1 = min(max(x0+1, 0), W_-1);
    const int yc0 = min(max(y0, 0), H_-1),   yc1 = min(max(y0+1, 0), H_-1);
    const bf16x8 v00 = *(const bf16x8*)(vb + (size_t)(yc0*W_ + xc0)*256);
    const bf16x8 v10 = *(const bf16x8*)(vb + (size_t)(yc0*W_ + xc1)*256);
    const bf16x8 v01 = *(const bf16x8*)(vb + (size_t)(yc1*W_ + xc0)*256);
    const bf16x8 v11 = *(const bf16x8*)(vb + (size_t)(yc1*W_ + xc1)*256);
#pragma unroll
    for (int c = 0; c < 8; ++c)
      a[c] += w00*(float)v00[c] + w10*(float)v10[c]
            + w01*(float)v01[c] + w11*(float)v11[c];
  }
  bf16 r[8];
#pragma unroll
  for (int c = 0; c < 8; ++c) r[c] = (bf16)a[c];
  *(bf16x8*)(agg + (size_t)t*256 + g*32 + c8*8) = *(bf16x8*)r;
}

// ---------------- LayerNorm over C=256, one wave per token ------------------
__global__ __launch_bounds__(256)
void ln_kernel(const float* __restrict__ x, const float* __restrict__ gg,
               const float* __restrict__ bb, float* __restrict__ yf,
               bf16* __restrict__ yb)
{
  const int tid = threadIdx.x;
  const int wave = tid >> 6, lane = tid & 63;
  const size_t tok = (size_t)blockIdx.x*4 + wave;
  const float4 v = ((const float4*)(x + tok*256))[lane];
  float s = v.x + v.y + v.z + v.w;
  float q = v.x*v.x + v.y*v.y + v.z*v.z + v.w*v.w;
#pragma unroll
  for (int o = 32; o; o >>= 1) { s += __shfl_xor(s, o, 64); q += __shfl_xor(q, o, 64); }
  const float mean = s * (1.f/256.f);
  const float var  = q * (1.f/256.f) - mean*mean;
  const float rs   = rsqrtf(var + 1e-5f);
  const int c = lane*4;
  float o0 = (v.x - mean)*rs*gg[c+0] + bb[c+0];
  float o1 = (v.y - mean)*rs*gg[c+1] + bb[c+1];
  float o2 = (v.z - mean)*rs*gg[c+2] + bb[c+2];
  float o3 = (v.w - mean)*rs*gg[c+3] + bb[c+3];
  yf[tok*256 + c + 0] = o0; yf[tok*256 + c + 1] = o1;
  yf[tok*256 + c + 2] = o2; yf[tok*256 + c + 3] = o3;
  yb[tok*256 + c + 0] = (bf16)o0; yb[tok*256 + c + 1] = (bf16)o1;
  yb[tok*256 + c + 2] = (bf16)o2; yb[tok*256 + c + 3] = (bf16)o3;
}

// ---------------- LN2 + transpose back to (B, C, H, W) ----------------------
__global__ __launch_bounds__(256)
void ln2_out_kernel(const float* __restrict__ x, const float* __restrict__ gg,
                    const float* __restrict__ bb, float* __restrict__ out)
{
  __shared__ float lt[32][257];
  const int tid = threadIdx.x, wave = tid >> 6, lane = tid & 63;
  const int tok0 = blockIdx.x * 32;
#pragma unroll
  for (int t8 = 0; t8 < 8; ++t8) {
    const int tl = wave*8 + t8;
    const size_t tok = tok0 + tl;
    const float4 v = ((const float4*)(x + tok*256))[lane];
    float s = v.x + v.y + v.z + v.w;
    float q = v.x*v.x + v.y*v.y + v.z*v.z + v.w*v.w;
#pragma unroll
    for (int o = 32; o; o >>= 1) { s += __shfl_xor(s, o, 64); q += __shfl_xor(q, o, 64); }
    const float mean = s * (1.f/256.f);
    const float var  = q * (1.f/256.f) - mean*mean;
    const float rs   = rsqrtf(var + 1e-5f);
    const int c = lane*4;
    lt[tl][c+0] = (v.x - mean)*rs*gg[c+0] + bb[c+0];
    lt[tl][c+1] = (v.y - mean)*rs*gg[c+1] + bb[c+1];
    lt[tl][c+2] = (v.z - mean)*rs*gg[c+2] + bb[c+2];
    lt[tl][c+3] = (v.w - mean)*rs*gg[c+3] + bb[c+3];
  }
  __syncthreads();
  const int b  = tok0 / HW_;
  const int n0 = tok0 % HW_;
#pragma unroll
  for (int it = 0; it < 32; ++it) {
    int flat = it*256 + tid;
    int c = flat >> 5, tl = flat & 31;
    out[((size_t)(b*C_ + c))*HW_ + n0 + tl] = lt[tl][c];
  }
}

// ---------------- host-side orchestration -----------------------------------
extern "C" void kernel_launch(void* const* d_in, const int* in_sizes, int n_in,
                              void* d_out, int out_size, void* d_ws, size_t ws_size,
                              hipStream_t stream)
{
  const float* feats   = (const float*)d_in[0];
  const float* featsp  = (const float*)d_in[1];
  const float* anchors = (const float*)d_in[2];
  const float* value_W = (const float*)d_in[3];
  const float* value_b = (const float*)d_in[4];
  const float* off_W   = (const float*)d_in[5];
  const float* off_b   = (const float*)d_in[6];
  const float* attn_W  = (const float*)d_in[7];
  const float* attn_b  = (const float*)d_in[8];
  const float* out_W   = (const float*)d_in[9];
  const float* out_b   = (const float*)d_in[10];
  const float* ln1_g   = (const float*)d_in[11];
  const float* ln1_b   = (const float*)d_in[12];
  const float* ln2_g   = (const float*)d_in[13];
  const float* ln2_b   = (const float*)d_in[14];
  const float* w1      = (const float*)d_in[15];
  const float* b1      = (const float*)d_in[16];
  const float* w2      = (const float*)d_in[17];
  const float* b2      = (const float*)d_in[18];
  float* out = (float*)d_out;

  char* ws = (char*)d_ws;
  size_t cur = 0;
  auto alloc = [&](size_t bytes) -> char* {
    char* p = ws + cur;
    cur += (bytes + 255) & ~(size_t)255;
    return p;
  };
  bf16*  wqkv  = (bf16*) alloc((size_t)NQKVP*256*2);
  bf16*  woutt = (bf16*) alloc((size_t)256*256*2);
  bf16*  w1b   = (bf16*) alloc((size_t)512*256*2);
  bf16*  w2b   = (bf16*) alloc((size_t)256*512*2);
  float* bqkv  = (float*)alloc((size_t)NQKVP*4);
  float* qf    = (float*)alloc((size_t)NTOK*256*4);   // reused as x2
  bf16*  qb    = (bf16*) alloc((size_t)NTOK*256*2);   // reused as agg
  bf16*  valb  = (bf16*) alloc((size_t)NTOK*256*2);   // x1 overlays valb+offv
  float* offv  = (float*)alloc((size_t)NTOK*128*4);
  float* attnl = (float*)alloc((size_t)NTOK*64*4);
  float* y1f   = (float*)alloc((size_t)NTOK*256*4);
  bf16*  y1b   = (bf16*) alloc((size_t)NTOK*256*2);
  bf16*  hb    = (bf16*) alloc((size_t)NTOK*512*2);
  float* x1   = (float*)valb;   // 26.2 MB overlay (valb+offv dead after sampling)
  float* x2   = qf;             // q dead after gemm<1> epilogue
  bf16*  aggb = qb;             // q_bf16 dead after gemm<0>

  prep_weights<<<(NQKVP*256 + 256*256 + 512*256 + 256*512 + NQKVP + 255)/256, 256, 0, stream>>>(
      value_W, value_b, off_W, off_b, attn_W, attn_b, out_W, w1, w2,
      wqkv, bqkv, woutt, w1b, w2b);

  qprep_kernel<<<dim3(HW_/64, C_/64, B_), 256, 0, stream>>>(feats, featsp, qf, qb);

  gemm_kernel<0, 256><<<dim3(NTOK/128, NQKVP/128), 256, 0, stream>>>(
      qb, wqkv, bqkv, valb, offv, attnl, nullptr);

  sample_kernel<<<NTOK/8, 256, 0, stream>>>(valb, offv, attnl, anchors, aggb);

  gemm_kernel<1, 256><<<dim3(NTOK/128, 256/128), 256, 0, stream>>>(
      aggb, woutt, out_b, x1, nullptr, nullptr, qf);

  ln_kernel<<<NTOK/4, 256, 0, stream>>>(x1, ln1_g, ln1_b, y1f, y1b);

  gemm_kernel<2, 256><<<dim3(NTOK/128, 512/128), 256, 0, stream>>>(
      y1b, w1b, b1, hb, nullptr, nullptr, nullptr);

  gemm_kernel<3, 512><<<dim3(NTOK/128, 256/128), 256, 0, stream>>>(
      hb, w2b, b2, x2, nullptr, nullptr, y1f);

  ln2_out_kernel<<<NTOK/32, 256, 0, stream>>>(x2, ln2_g, ln2_b, out);
}

// Round 4
// 152.865 us; speedup vs baseline: 2.1054x; 1.1631x over previous
//
#include <hip/hip_runtime.h>
#include <hip/hip_bf16.h>
#include <math.h>
#include <stdint.h>

#define B_ 2
#define C_ 256
#define H_ 80
#define W_ 160
#define HW_ (H_*W_)      // 12800
#define NTOK (B_*HW_)    // 25600
#define G_ 8
#define P_ 8
#define NQKV 448         // 256 val + 128 off + 64 attn (padded to 512 for tiles)
#define NQKVP 512

typedef __bf16 bf16;
typedef __attribute__((ext_vector_type(8))) __bf16 bf16x8;
typedef __attribute__((ext_vector_type(4))) float f32x4;

__device__ __forceinline__ void gload_lds16(const void* g, void* l) {
  __builtin_amdgcn_global_load_lds(
      (__attribute__((address_space(1))) void*)g,
      (__attribute__((address_space(3))) void*)l,
      16, 0, 0);
}

// ---------------- weight prep: transpose to [N][K] bf16, concat+pad qkv -----
__global__ __launch_bounds__(256)
void prep_weights(const float* __restrict__ vW, const float* __restrict__ vb,
                  const float* __restrict__ oW, const float* __restrict__ ob,
                  const float* __restrict__ aW, const float* __restrict__ ab,
                  const float* __restrict__ outW,
                  const float* __restrict__ w1, const float* __restrict__ w2,
                  bf16* __restrict__ wqkv, float* __restrict__ bqkv,
                  bf16* __restrict__ woutt, bf16* __restrict__ w1b, bf16* __restrict__ w2b)
{
  int i = blockIdx.x * 256 + threadIdx.x;
  if (i < NQKVP*256) {                      // wqkv_t[n][k], zero-padded rows
    int nn = i >> 8, k = i & 255;
    float w;
    if (nn < 256)      w = vW[k*256 + nn];
    else if (nn < 384) w = oW[k*128 + (nn-256)];
    else if (nn < 448) w = aW[k*64  + (nn-384)];
    else               w = 0.f;
    wqkv[i] = (bf16)w;
  }
  int j = i - NQKVP*256;
  if (j >= 0 && j < 256*256) {              // outW_t[n][k]
    int nn = j >> 8, k = j & 255;
    woutt[j] = (bf16)outW[k*256 + nn];
  }
  int j2 = i - (NQKVP*256 + 256*256);
  if (j2 >= 0 && j2 < 512*256) w1b[j2] = (bf16)w1[j2];   // already [N][K]
  int j3 = i - (NQKVP*256 + 256*256 + 512*256);
  if (j3 >= 0 && j3 < 256*512) w2b[j3] = (bf16)w2[j3];   // already [N][K]
  int j4 = i - (NQKVP*256 + 256*256 + 512*256 + 256*512);
  if (j4 >= 0 && j4 < NQKVP) {
    float bv;
    if (j4 < 256)      bv = vb[j4];
    else if (j4 < 384) bv = ob[j4-256];
    else if (j4 < 448) bv = ab[j4-384];
    else               bv = 0.f;
    bqkv[j4] = bv;
  }
}

// ---------------- q = (feats+feats_pos) transposed NCHW -> (tok, C) bf16 ----
__global__ __launch_bounds__(256)
void qprep_kernel(const float* __restrict__ f, const float* __restrict__ fp,
                  bf16* __restrict__ qb)
{
  __shared__ float lt[64][65];
  const int tid = threadIdx.x;
  const int n0 = blockIdx.x * 64;   // token tile
  const int c0 = blockIdx.y * 64;   // channel tile
  const int b  = blockIdx.z;
#pragma unroll
  for (int i = 0; i < 16; ++i) {
    int cl = i*4 + (tid >> 6), nl = tid & 63;
    size_t gi = ((size_t)(b*C_ + c0 + cl))*HW_ + n0 + nl;
    lt[cl][nl] = f[gi] + fp[gi];
  }
  __syncthreads();
#pragma unroll
  for (int i = 0; i < 16; ++i) {
    int nl = i*4 + (tid >> 6), cl = tid & 63;
    size_t qi = ((size_t)(b*HW_ + n0 + nl))*C_ + c0 + cl;
    qb[qi] = (bf16)lt[cl][nl];
  }
}

// ---------------- bf16 MFMA GEMM, 128x128 tile, BK=64, XOR-swizzled LDS -----
// C[M x N] = A[M x K] * Bt[N x K]^T  (m97-style structure)
// EPI 0: qkv  -> val bf16 / off f32 / attn-logit f32 (cols >= 448 dropped)
// EPI 2: ffn1 -> h = bf16(silu(acc+bias))
// EPI 3: ffn2 -> x2 = acc + bias + res(bf16)   (f32)
template<int EPI, int KTOT>
__global__ __launch_bounds__(256)
void gemm_kernel(const bf16* __restrict__ A, const bf16* __restrict__ Bt,
                 const float* __restrict__ bias,
                 void* __restrict__ out0, float* __restrict__ out1,
                 float* __restrict__ out2, const bf16* __restrict__ resb)
{
  __shared__ bf16 lA[128*64];   // 16 KB, [row][BK] with chunk-XOR swizzle
  __shared__ bf16 lB[128*64];   // 16 KB
  const int tid  = threadIdx.x;
  const int wave = tid >> 6, lane = tid & 63;
  const int m0 = blockIdx.x * 128, n0 = blockIdx.y * 128;
  const int wm = wave >> 1, wn = wave & 1;     // 2x2 wave grid, 64x64 each
  const int fr = lane & 15;
  const int fq = lane >> 4;
  f32x4 acc[4][4] = {};

  for (int kc = 0; kc < KTOT/64; ++kc) {
    if (kc) __syncthreads();
#pragma unroll
    for (int it = 0; it < 4; ++it) {
      int chunk = it*256 + tid;          // 16B-chunk index in 128x64 tile
      int row = chunk >> 3, cb = chunk & 7;
      int ksw = ((cb ^ (row & 7)) << 3); // swizzled k-element offset
      gload_lds16(A  + (size_t)(m0+row)*KTOT + kc*64 + ksw,
                  (char*)lA + it*4096 + wave*1024);
      gload_lds16(Bt + (size_t)(n0+row)*KTOT + kc*64 + ksw,
                  (char*)lB + it*4096 + wave*1024);
    }
    __syncthreads();
#pragma unroll
    for (int ks = 0; ks < 2; ++ks) {
      bf16x8 af[4], bg[4];
#pragma unroll
      for (int i = 0; i < 4; ++i) {
        int ar = wm*64 + i*16 + fr;
        af[i] = *(const bf16x8*)&lA[ar*64 + (((ks*4 + fq) ^ (ar & 7)) << 3)];
        int br = wn*64 + i*16 + fr;
        bg[i] = *(const bf16x8*)&lB[br*64 + (((ks*4 + fq) ^ (br & 7)) << 3)];
      }
#pragma unroll
      for (int mi = 0; mi < 4; ++mi)
#pragma unroll
        for (int ni = 0; ni < 4; ++ni)
          acc[mi][ni] = __builtin_amdgcn_mfma_f32_16x16x32_bf16(af[mi], bg[ni], acc[mi][ni], 0, 0, 0);
    }
  }

#pragma unroll
  for (int mi = 0; mi < 4; ++mi)
#pragma unroll
  for (int ni = 0; ni < 4; ++ni)
#pragma unroll
  for (int r = 0; r < 4; ++r) {
    int row = m0 + wm*64 + mi*16 + fq*4 + r;
    int col = n0 + wn*64 + ni*16 + fr;
    float v = acc[mi][ni][r] + bias[col];
    if (EPI == 0) {
      if (col < 256)      ((bf16*)out0)[(size_t)row*256 + col] = (bf16)v;
      else if (col < 384) out1[(size_t)row*128 + (col-256)] = v;
      else if (col < 448) out2[(size_t)row*64  + (col-384)] = v;
      // cols 448..511 are padding: dropped
    } else if (EPI == 2) {
      float s = v / (1.0f + __expf(-v));
      ((bf16*)out0)[(size_t)row*512 + col] = (bf16)s;
    } else {
      ((float*)out0)[(size_t)row*256 + col] = v + (float)resb[(size_t)row*256 + col];
    }
  }
}

// ---------------- out-proj GEMM + residual + fused LayerNorm1 ---------------
// BM=128, BN=256 (full row), 512 threads = 8 waves in 2(M)x4(N) grid.
// y1 = LN(res + A*Bt^T + bias); writes bf16 only.
__global__ __launch_bounds__(512)
void gemm_ln_kernel(const bf16* __restrict__ A, const bf16* __restrict__ Bt,
                    const float* __restrict__ bias, const bf16* __restrict__ res,
                    const float* __restrict__ gg, const float* __restrict__ bb,
                    bf16* __restrict__ y1b)
{
  __shared__ bf16 lA[128*64];   // 16 KB
  __shared__ bf16 lB[256*64];   // 32 KB
  __shared__ float2 red[128][4]; // per-row (sum, sumsq) per wn
  const int tid  = threadIdx.x;
  const int wave = tid >> 6, lane = tid & 63;
  const int m0 = blockIdx.x * 128;
  const int wm = wave >> 2, wn = wave & 3;     // 2x4 wave grid, 64x64 each
  const int fr = lane & 15;
  const int fq = lane >> 4;
  f32x4 acc[4][4] = {};

  for (int kc = 0; kc < 256/64; ++kc) {
    if (kc) __syncthreads();
#pragma unroll
    for (int it = 0; it < 2; ++it) {         // A: 1024 chunks / 512 thr
      int chunk = it*512 + tid;
      int row = chunk >> 3, cb = chunk & 7;
      int ksw = ((cb ^ (row & 7)) << 3);
      gload_lds16(A + (size_t)(m0+row)*256 + kc*64 + ksw,
                  (char*)lA + it*8192 + wave*1024);
    }
#pragma unroll
    for (int it = 0; it < 4; ++it) {         // B: 2048 chunks / 512 thr
      int chunk = it*512 + tid;
      int row = chunk >> 3, cb = chunk & 7;
      int ksw = ((cb ^ (row & 7)) << 3);
      gload_lds16(Bt + (size_t)row*256 + kc*64 + ksw,
                  (char*)lB + it*8192 + wave*1024);
    }
    __syncthreads();
#pragma unroll
    for (int ks = 0; ks < 2; ++ks) {
      bf16x8 af[4], bg[4];
#pragma unroll
      for (int i = 0; i < 4; ++i) {
        int ar = wm*64 + i*16 + fr;
        af[i] = *(const bf16x8*)&lA[ar*64 + (((ks*4 + fq) ^ (ar & 7)) << 3)];
        int br = wn*64 + i*16 + fr;
        bg[i] = *(const bf16x8*)&lB[br*64 + (((ks*4 + fq) ^ (br & 7)) << 3)];
      }
#pragma unroll
      for (int mi = 0; mi < 4; ++mi)
#pragma unroll
        for (int ni = 0; ni < 4; ++ni)
          acc[mi][ni] = __builtin_amdgcn_mfma_f32_16x16x32_bf16(af[mi], bg[ni], acc[mi][ni], 0, 0, 0);
    }
  }

  // epilogue: v = acc + bias + res; per-row LN stats; normalized bf16 write
  float gcol[4], bcol[4];
#pragma unroll
  for (int ni = 0; ni < 4; ++ni) {
    int col = wn*64 + ni*16 + fr;
    gcol[ni] = gg[col]; bcol[ni] = bb[col];
  }
#pragma unroll
  for (int mi = 0; mi < 4; ++mi)
#pragma unroll
  for (int r = 0; r < 4; ++r) {
    int rowl = wm*64 + mi*16 + fq*4 + r;
    size_t rowg = (size_t)(m0 + rowl);
    float s = 0.f, q = 0.f;
#pragma unroll
    for (int ni = 0; ni < 4; ++ni) {
      int col = wn*64 + ni*16 + fr;
      float v = acc[mi][ni][r] + bias[col] + (float)res[rowg*256 + col];
      acc[mi][ni][r] = v;
      s += v; q += v*v;
    }
#pragma unroll
    for (int o = 1; o < 16; o <<= 1) { s += __shfl_xor(s, o, 64); q += __shfl_xor(q, o, 64); }
    if (fr == 0) red[rowl][wn] = make_float2(s, q);
  }
  __syncthreads();
#pragma unroll
  for (int mi = 0; mi < 4; ++mi)
#pragma unroll
  for (int r = 0; r < 4; ++r) {
    int rowl = wm*64 + mi*16 + fq*4 + r;
    size_t rowg = (size_t)(m0 + rowl);
    float s = 0.f, q = 0.f;
#pragma unroll
    for (int k = 0; k < 4; ++k) { float2 p = red[rowl][k]; s += p.x; q += p.y; }
    const float mean = s * (1.f/256.f);
    const float var  = q * (1.f/256.f) - mean*mean;
    const float rs   = rsqrtf(var + 1e-5f);
#pragma unroll
    for (int ni = 0; ni < 4; ++ni) {
      int col = wn*64 + ni*16 + fr;
      float y = (acc[mi][ni][r] - mean)*rs*gcol[ni] + bcol[ni];
      y1b[rowg*256 + col] = (bf16)y;
    }
  }
}

// ---------------- softmax + deformable bilinear sampling + aggregate --------
__global__ __launch_bounds__(256)
void sample_kernel(const bf16* __restrict__ val, const float* __restrict__ off,
                   const float* __restrict__ attnl, const float* __restrict__ anchors,
                   bf16* __restrict__ agg)
{
  const int tid  = threadIdx.x;
  const int lane = tid & 63;
  const int wv   = tid >> 6;
  const int tsub = lane >> 5;
  const int g    = (lane >> 2) & 7;
  const int c8   = lane & 3;
  const int t    = blockIdx.x * 8 + wv * 2 + tsub;
  const int b    = t / HW_;

  const float2 anc = *(const float2*)(anchors + (size_t)t*2);
  const float ax = anc.x * W_ - 0.5f;
  const float ay = anc.y * H_ - 0.5f;

  const float4 l0 = *(const float4*)(attnl + (size_t)t*64 + g*8);
  const float4 l1 = *(const float4*)(attnl + (size_t)t*64 + g*8 + 4);
  float l[8] = {l0.x, l0.y, l0.z, l0.w, l1.x, l1.y, l1.z, l1.w};
  float mx = l[0];
#pragma unroll
  for (int p = 1; p < 8; ++p) mx = fmaxf(mx, l[p]);
  float s = 0.f;
#pragma unroll
  for (int p = 0; p < 8; ++p) { l[p] = __expf(l[p] - mx); s += l[p]; }
  const float inv = 1.f / s;

  const float4* opv = (const float4*)(off + (size_t)t*128 + g*16);
  const float4 o0 = opv[0], o1 = opv[1], o2 = opv[2], o3 = opv[3];
  const float ox[8] = {o0.x, o0.z, o1.x, o1.z, o2.x, o2.z, o3.x, o3.z};
  const float oy[8] = {o0.y, o0.w, o1.y, o1.w, o2.y, o2.w, o3.y, o3.w};

  const bf16* vb = val + ((size_t)b*HW_)*256 + g*32 + c8*8;

  float a[8] = {};
#pragma unroll
  for (int p = 0; p < 8; ++p) {
    const float px = ax + ox[p], py = ay + oy[p];
    const float x0f = floorf(px), y0f = floorf(py);
    const int x0 = (int)x0f, y0 = (int)y0f;
    const float wx1 = px - x0f, wx0 = 1.f - wx1;
    const float wy1 = py - y0f, wy0 = 1.f - wy1;
    const float ap = l[p] * inv;
    float w00 = ap*wx0*wy0, w10 = ap*wx1*wy0, w01 = ap*wx0*wy1, w11 = ap*wx1*wy1;
    const bool vx0 = (unsigned)x0 < W_, vx1 = (unsigned)(x0+1) < W_;
    const bool vy0 = (unsigned)y0 < H_, vy1 = (unsigned)(y0+1) < H_;
    w00 = (vx0 && vy0) ? w00 : 0.f;  w10 = (vx1 && vy0) ? w10 : 0.f;
    w01 = (vx0 && vy1) ? w01 : 0.f;  w11 = (vx1 && vy1) ? w11 : 0.f;
    const int xc0 = min(max(x0, 0), W_-1),   xc1 = min(max(x0+1, 0), W_-1);
    const int yc0 = min(max(y0, 0), H_-1),   yc1 = min(max(y0+1, 0), H_-1);
    const bf16x8 v00 = *(const bf16x8*)(vb + (size_t)(yc0*W_ + xc0)*256);
    const bf16x8 v10 = *(const bf16x8*)(vb + (size_t)(yc0*W_ + xc1)*256);
    const bf16x8 v01 = *(const bf16x8*)(vb + (size_t)(yc1*W_ + xc0)*256);
    const bf16x8 v11 = *(const bf16x8*)(vb + (size_t)(yc1*W_ + xc1)*256);
#pragma unroll
    for (int c = 0; c < 8; ++c)
      a[c] += w00*(float)v00[c] + w10*(float)v10[c]
            + w01*(float)v01[c] + w11*(float)v11[c];
  }
  bf16 r[8];
#pragma unroll
  for (int c = 0; c < 8; ++c) r[c] = (bf16)a[c];
  *(bf16x8*)(agg + (size_t)t*256 + g*32 + c8*8) = *(bf16x8*)r;
}

// ---------------- LN2 + transpose back to (B, C, H, W) ----------------------
__global__ __launch_bounds__(256)
void ln2_out_kernel(const float* __restrict__ x, const float* __restrict__ gg,
                    const float* __restrict__ bb, float* __restrict__ out)
{
  __shared__ float lt[32][257];
  const int tid = threadIdx.x, wave = tid >> 6, lane = tid & 63;
  const int tok0 = blockIdx.x * 32;
#pragma unroll
  for (int t8 = 0; t8 < 8; ++t8) {
    const int tl = wave*8 + t8;
    const size_t tok = tok0 + tl;
    const float4 v = ((const float4*)(x + tok*256))[lane];
    float s = v.x + v.y + v.z + v.w;
    float q = v.x*v.x + v.y*v.y + v.z*v.z + v.w*v.w;
#pragma unroll
    for (int o = 32; o; o >>= 1) { s += __shfl_xor(s, o, 64); q += __shfl_xor(q, o, 64); }
    const float mean = s * (1.f/256.f);
    const float var  = q * (1.f/256.f) - mean*mean;
    const float rs   = rsqrtf(var + 1e-5f);
    const int c = lane*4;
    lt[tl][c+0] = (v.x - mean)*rs*gg[c+0] + bb[c+0];
    lt[tl][c+1] = (v.y - mean)*rs*gg[c+1] + bb[c+1];
    lt[tl][c+2] = (v.z - mean)*rs*gg[c+2] + bb[c+2];
    lt[tl][c+3] = (v.w - mean)*rs*gg[c+3] + bb[c+3];
  }
  __syncthreads();
  const int b  = tok0 / HW_;
  const int n0 = tok0 % HW_;
#pragma unroll
  for (int it = 0; it < 32; ++it) {
    int flat = it*256 + tid;
    int c = flat >> 5, tl = flat & 31;
    out[((size_t)(b*C_ + c))*HW_ + n0 + tl] = lt[tl][c];
  }
}

// ---------------- host-side orchestration -----------------------------------
extern "C" void kernel_launch(void* const* d_in, const int* in_sizes, int n_in,
                              void* d_out, int out_size, void* d_ws, size_t ws_size,
                              hipStream_t stream)
{
  const float* feats   = (const float*)d_in[0];
  const float* featsp  = (const float*)d_in[1];
  const float* anchors = (const float*)d_in[2];
  const float* value_W = (const float*)d_in[3];
  const float* value_b = (const float*)d_in[4];
  const float* off_W   = (const float*)d_in[5];
  const float* off_b   = (const float*)d_in[6];
  const float* attn_W  = (const float*)d_in[7];
  const float* attn_b  = (const float*)d_in[8];
  const float* out_W   = (const float*)d_in[9];
  const float* out_b   = (const float*)d_in[10];
  const float* ln1_g   = (const float*)d_in[11];
  const float* ln1_b   = (const float*)d_in[12];
  const float* ln2_g   = (const float*)d_in[13];
  const float* ln2_b   = (const float*)d_in[14];
  const float* w1      = (const float*)d_in[15];
  const float* b1      = (const float*)d_in[16];
  const float* w2      = (const float*)d_in[17];
  const float* b2      = (const float*)d_in[18];
  float* out = (float*)d_out;

  char* ws = (char*)d_ws;
  size_t cur = 0;
  auto alloc = [&](size_t bytes) -> char* {
    char* p = ws + cur;
    cur += (bytes + 255) & ~(size_t)255;
    return p;
  };
  bf16*  wqkv  = (bf16*) alloc((size_t)NQKVP*256*2);
  bf16*  woutt = (bf16*) alloc((size_t)256*256*2);
  bf16*  w1b   = (bf16*) alloc((size_t)512*256*2);
  bf16*  w2b   = (bf16*) alloc((size_t)256*512*2);
  float* bqkv  = (float*)alloc((size_t)NQKVP*4);
  bf16*  qb    = (bf16*) alloc((size_t)NTOK*256*2);   // live until gemm_ln (residual)
  bf16*  valb  = (bf16*) alloc((size_t)NTOK*256*2);
  float* offv  = (float*)alloc((size_t)NTOK*128*4);
  float* attnl = (float*)alloc((size_t)NTOK*64*4);
  bf16*  aggb  = (bf16*) alloc((size_t)NTOK*256*2);
  bf16*  y1b   = (bf16*) alloc((size_t)NTOK*256*2);
  bf16*  hb    = (bf16*) alloc((size_t)NTOK*512*2);
  float* x2    = (float*)alloc((size_t)NTOK*256*4);

  prep_weights<<<(NQKVP*256 + 256*256 + 512*256 + 256*512 + NQKVP + 255)/256, 256, 0, stream>>>(
      value_W, value_b, off_W, off_b, attn_W, attn_b, out_W, w1, w2,
      wqkv, bqkv, woutt, w1b, w2b);

  qprep_kernel<<<dim3(HW_/64, C_/64, B_), 256, 0, stream>>>(feats, featsp, qb);

  gemm_kernel<0, 256><<<dim3(NTOK/128, NQKVP/128), 256, 0, stream>>>(
      qb, wqkv, bqkv, valb, offv, attnl, nullptr);

  sample_kernel<<<NTOK/8, 256, 0, stream>>>(valb, offv, attnl, anchors, aggb);

  gemm_ln_kernel<<<NTOK/128, 512, 0, stream>>>(
      aggb, woutt, out_b, qb, ln1_g, ln1_b, y1b);

  gemm_kernel<2, 256><<<dim3(NTOK/128, 512/128), 256, 0, stream>>>(
      y1b, w1b, b1, hb, nullptr, nullptr, nullptr);

  gemm_kernel<3, 512><<<dim3(NTOK/128, 256/128), 256, 0, stream>>>(
      hb, w2b, b2, x2, nullptr, nullptr, y1b);

  ln2_out_kernel<<<NTOK/32, 256, 0, stream>>>(x2, ln2_g, ln2_b, out);
}

// Round 5
// 145.489 us; speedup vs baseline: 2.2121x; 1.0507x over previous
//
#include <hip/hip_runtime.h>
#include <hip/hip_bf16.h>
#include <math.h>
#include <stdint.h>

#define B_ 2
#define C_ 256
#define H_ 80
#define W_ 160
#define HW_ (H_*W_)      // 12800
#define NTOK (B_*HW_)    // 25600
#define G_ 8
#define P_ 8
#define NQKV 448         // 256 val + 128 off + 64 attn (padded to 512 for tiles)
#define NQKVP 512

typedef __bf16 bf16;
typedef __attribute__((ext_vector_type(8))) __bf16 bf16x8;
typedef __attribute__((ext_vector_type(4))) float f32x4;

__device__ __forceinline__ void gload_lds16(const void* g, void* l) {
  __builtin_amdgcn_global_load_lds(
      (__attribute__((address_space(1))) void*)g,
      (__attribute__((address_space(3))) void*)l,
      16, 0, 0);
}

// ---------------- weight prep: transpose to [N][K] bf16, concat+pad qkv -----
__global__ __launch_bounds__(256)
void prep_weights(const float* __restrict__ vW, const float* __restrict__ vb,
                  const float* __restrict__ oW, const float* __restrict__ ob,
                  const float* __restrict__ aW, const float* __restrict__ ab,
                  const float* __restrict__ outW,
                  const float* __restrict__ w1, const float* __restrict__ w2,
                  bf16* __restrict__ wqkv, float* __restrict__ bqkv,
                  bf16* __restrict__ woutt, bf16* __restrict__ w1b, bf16* __restrict__ w2b)
{
  int i = blockIdx.x * 256 + threadIdx.x;
  if (i < NQKVP*256) {                      // wqkv_t[n][k], zero-padded rows
    int nn = i >> 8, k = i & 255;
    float w;
    if (nn < 256)      w = vW[k*256 + nn];
    else if (nn < 384) w = oW[k*128 + (nn-256)];
    else if (nn < 448) w = aW[k*64  + (nn-384)];
    else               w = 0.f;
    wqkv[i] = (bf16)w;
  }
  int j = i - NQKVP*256;
  if (j >= 0 && j < 256*256) {              // outW_t[n][k]
    int nn = j >> 8, k = j & 255;
    woutt[j] = (bf16)outW[k*256 + nn];
  }
  int j2 = i - (NQKVP*256 + 256*256);
  if (j2 >= 0 && j2 < 512*256) w1b[j2] = (bf16)w1[j2];   // already [N][K]
  int j3 = i - (NQKVP*256 + 256*256 + 512*256);
  if (j3 >= 0 && j3 < 256*512) w2b[j3] = (bf16)w2[j3];   // already [N][K]
  int j4 = i - (NQKVP*256 + 256*256 + 512*256 + 256*512);
  if (j4 >= 0 && j4 < NQKVP) {
    float bv;
    if (j4 < 256)      bv = vb[j4];
    else if (j4 < 384) bv = ob[j4-256];
    else if (j4 < 448) bv = ab[j4-384];
    else               bv = 0.f;
    bqkv[j4] = bv;
  }
}

// ---------------- q = (feats+feats_pos) transposed NCHW -> (tok, C) bf16 ----
__global__ __launch_bounds__(256)
void qprep_kernel(const float* __restrict__ f, const float* __restrict__ fp,
                  bf16* __restrict__ qb)
{
  __shared__ float lt[64][65];
  const int tid = threadIdx.x;
  const int n0 = blockIdx.x * 64;   // token tile
  const int c0 = blockIdx.y * 64;   // channel tile
  const int b  = blockIdx.z;
#pragma unroll
  for (int i = 0; i < 16; ++i) {
    int cl = i*4 + (tid >> 6), nl = tid & 63;
    size_t gi = ((size_t)(b*C_ + c0 + cl))*HW_ + n0 + nl;
    lt[cl][nl] = f[gi] + fp[gi];
  }
  __syncthreads();
#pragma unroll
  for (int i = 0; i < 16; ++i) {
    int nl = i*4 + (tid >> 6), cl = tid & 63;
    size_t qi = ((size_t)(b*HW_ + n0 + nl))*C_ + c0 + cl;
    qb[qi] = (bf16)lt[cl][nl];
  }
}

// ---------------- bf16 MFMA GEMM, 128x128 tile, BK=64, XOR-swizzled LDS -----
// EPI 0: qkv  -> val bf16 / off f32 / attn-logit f32 (cols >= 448 dropped)
// EPI 2: ffn1 -> h = bf16(silu(acc+bias))
template<int EPI, int KTOT>
__global__ __launch_bounds__(256)
void gemm_kernel(const bf16* __restrict__ A, const bf16* __restrict__ Bt,
                 const float* __restrict__ bias,
                 void* __restrict__ out0, float* __restrict__ out1,
                 float* __restrict__ out2)
{
  __shared__ bf16 lA[128*64];   // 16 KB, [row][BK] with chunk-XOR swizzle
  __shared__ bf16 lB[128*64];   // 16 KB
  const int tid  = threadIdx.x;
  const int wave = tid >> 6, lane = tid & 63;
  const int m0 = blockIdx.x * 128, n0 = blockIdx.y * 128;
  const int wm = wave >> 1, wn = wave & 1;     // 2x2 wave grid, 64x64 each
  const int fr = lane & 15;
  const int fq = lane >> 4;
  f32x4 acc[4][4] = {};

  for (int kc = 0; kc < KTOT/64; ++kc) {
    if (kc) __syncthreads();
#pragma unroll
    for (int it = 0; it < 4; ++it) {
      int chunk = it*256 + tid;          // 16B-chunk index in 128x64 tile
      int row = chunk >> 3, cb = chunk & 7;
      int ksw = ((cb ^ (row & 7)) << 3); // swizzled k-element offset
      gload_lds16(A  + (size_t)(m0+row)*KTOT + kc*64 + ksw,
                  (char*)lA + it*4096 + wave*1024);
      gload_lds16(Bt + (size_t)(n0+row)*KTOT + kc*64 + ksw,
                  (char*)lB + it*4096 + wave*1024);
    }
    __syncthreads();
#pragma unroll
    for (int ks = 0; ks < 2; ++ks) {
      bf16x8 af[4], bg[4];
#pragma unroll
      for (int i = 0; i < 4; ++i) {
        int ar = wm*64 + i*16 + fr;
        af[i] = *(const bf16x8*)&lA[ar*64 + (((ks*4 + fq) ^ (ar & 7)) << 3)];
        int br = wn*64 + i*16 + fr;
        bg[i] = *(const bf16x8*)&lB[br*64 + (((ks*4 + fq) ^ (br & 7)) << 3)];
      }
#pragma unroll
      for (int mi = 0; mi < 4; ++mi)
#pragma unroll
        for (int ni = 0; ni < 4; ++ni)
          acc[mi][ni] = __builtin_amdgcn_mfma_f32_16x16x32_bf16(af[mi], bg[ni], acc[mi][ni], 0, 0, 0);
    }
  }

#pragma unroll
  for (int mi = 0; mi < 4; ++mi)
#pragma unroll
  for (int ni = 0; ni < 4; ++ni)
#pragma unroll
  for (int r = 0; r < 4; ++r) {
    int row = m0 + wm*64 + mi*16 + fq*4 + r;
    int col = n0 + wn*64 + ni*16 + fr;
    float v = acc[mi][ni][r] + bias[col];
    if (EPI == 0) {
      if (col < 256)      ((bf16*)out0)[(size_t)row*256 + col] = (bf16)v;
      else if (col < 384) out1[(size_t)row*128 + (col-256)] = v;
      else if (col < 448) out2[(size_t)row*64  + (col-384)] = v;
      // cols 448..511 are padding: dropped
    } else {
      float s = v / (1.0f + __expf(-v));
      ((bf16*)out0)[(size_t)row*512 + col] = (bf16)s;
    }
  }
}

// ---------------- GEMM (BM=128, BN=256 full row) + residual + LayerNorm -----
// 512 threads = 8 waves in 2(M)x4(N) grid; y = LN(res + A*Bt^T + bias).
// NCHW_OUT=false: write bf16 token-major (LN1 -> y1b).
// NCHW_OUT=true : write f32 NCHW via LDS retile (LN2 -> final output).
template<int KTOT, bool NCHW_OUT>
__global__ __launch_bounds__(512)
void gemm_ln_kernel(const bf16* __restrict__ A, const bf16* __restrict__ Bt,
                    const float* __restrict__ bias, const bf16* __restrict__ res,
                    const float* __restrict__ gg, const float* __restrict__ bb,
                    bf16* __restrict__ yb, float* __restrict__ outf)
{
  __shared__ __align__(16) char smem[49152];   // lA(16K)+lB(32K); reused as lt
  bf16* lA = (bf16*)smem;
  bf16* lB = (bf16*)(smem + 16384);
  float (*lt)[132] = (float(*)[132])smem;      // 64 ch x 128 tok retile (33.8K)
  __shared__ float2 red[128][4];               // per-row (sum, sumsq) per wn
  const int tid  = threadIdx.x;
  const int wave = tid >> 6, lane = tid & 63;
  const int m0 = blockIdx.x * 128;
  const int wm = wave >> 2, wn = wave & 3;     // 2x4 wave grid, 64x64 each
  const int fr = lane & 15;
  const int fq = lane >> 4;
  f32x4 acc[4][4] = {};

  for (int kc = 0; kc < KTOT/64; ++kc) {
    if (kc) __syncthreads();
#pragma unroll
    for (int it = 0; it < 2; ++it) {         // A: 1024 chunks / 512 thr
      int chunk = it*512 + tid;
      int row = chunk >> 3, cb = chunk & 7;
      int ksw = ((cb ^ (row & 7)) << 3);
      gload_lds16(A + (size_t)(m0+row)*KTOT + kc*64 + ksw,
                  (char*)lA + it*8192 + wave*1024);
    }
#pragma unroll
    for (int it = 0; it < 4; ++it) {         // B: 2048 chunks / 512 thr
      int chunk = it*512 + tid;
      int row = chunk >> 3, cb = chunk & 7;
      int ksw = ((cb ^ (row & 7)) << 3);
      gload_lds16(Bt + (size_t)row*KTOT + kc*64 + ksw,
                  (char*)lB + it*8192 + wave*1024);
    }
    __syncthreads();
#pragma unroll
    for (int ks = 0; ks < 2; ++ks) {
      bf16x8 af[4], bg[4];
#pragma unroll
      for (int i = 0; i < 4; ++i) {
        int ar = wm*64 + i*16 + fr;
        af[i] = *(const bf16x8*)&lA[ar*64 + (((ks*4 + fq) ^ (ar & 7)) << 3)];
        int br = wn*64 + i*16 + fr;
        bg[i] = *(const bf16x8*)&lB[br*64 + (((ks*4 + fq) ^ (br & 7)) << 3)];
      }
#pragma unroll
      for (int mi = 0; mi < 4; ++mi)
#pragma unroll
        for (int ni = 0; ni < 4; ++ni)
          acc[mi][ni] = __builtin_amdgcn_mfma_f32_16x16x32_bf16(af[mi], bg[ni], acc[mi][ni], 0, 0, 0);
    }
  }

  // v = acc + bias + res; per-row LN stats via 16-lane reduce + LDS combine
  float gcol[4], bcol[4];
#pragma unroll
  for (int ni = 0; ni < 4; ++ni) {
    int col = wn*64 + ni*16 + fr;
    gcol[ni] = gg[col]; bcol[ni] = bb[col];
  }
#pragma unroll
  for (int mi = 0; mi < 4; ++mi)
#pragma unroll
  for (int r = 0; r < 4; ++r) {
    int rowl = wm*64 + mi*16 + fq*4 + r;
    size_t rowg = (size_t)(m0 + rowl);
    float s = 0.f, q = 0.f;
#pragma unroll
    for (int ni = 0; ni < 4; ++ni) {
      int col = wn*64 + ni*16 + fr;
      float v = acc[mi][ni][r] + bias[col] + (float)res[rowg*256 + col];
      acc[mi][ni][r] = v;
      s += v; q += v*v;
    }
#pragma unroll
    for (int o = 1; o < 16; o <<= 1) { s += __shfl_xor(s, o, 64); q += __shfl_xor(q, o, 64); }
    if (fr == 0) red[rowl][wn] = make_float2(s, q);
  }
  __syncthreads();
#pragma unroll
  for (int mi = 0; mi < 4; ++mi)
#pragma unroll
  for (int r = 0; r < 4; ++r) {
    int rowl = wm*64 + mi*16 + fq*4 + r;
    float s = 0.f, q = 0.f;
#pragma unroll
    for (int k = 0; k < 4; ++k) { float2 p = red[rowl][k]; s += p.x; q += p.y; }
    const float mean = s * (1.f/256.f);
    const float var  = q * (1.f/256.f) - mean*mean;
    const float rs   = rsqrtf(var + 1e-5f);
#pragma unroll
    for (int ni = 0; ni < 4; ++ni)
      acc[mi][ni][r] = (acc[mi][ni][r] - mean)*rs*gcol[ni] + bcol[ni];
  }

  if constexpr (!NCHW_OUT) {
#pragma unroll
    for (int mi = 0; mi < 4; ++mi)
#pragma unroll
    for (int ni = 0; ni < 4; ++ni)
#pragma unroll
    for (int r = 0; r < 4; ++r) {
      size_t rowg = (size_t)(m0 + wm*64 + mi*16 + fq*4 + r);
      int col = wn*64 + ni*16 + fr;
      yb[rowg*256 + col] = (bf16)acc[mi][ni][r];
    }
  } else {
    // retile through LDS: 4 chunks of 64 channels, coalesced NCHW f32 writes
    const int bq = m0 / HW_;
    const int n0 = m0 % HW_;
    __syncthreads();   // lA/lB fully consumed; safe to overlay lt
#pragma unroll
    for (int ch = 0; ch < 4; ++ch) {
      if (ch) __syncthreads();
      if (wn == ch) {
#pragma unroll
        for (int mi = 0; mi < 4; ++mi)
#pragma unroll
        for (int ni = 0; ni < 4; ++ni)
#pragma unroll
        for (int r = 0; r < 4; ++r)
          lt[ni*16 + fr][wm*64 + mi*16 + fq*4 + r] = acc[mi][ni][r];
      }
      __syncthreads();
#pragma unroll
      for (int j = 0; j < 4; ++j) {
        int flat = j*2048 + tid*4;
        int cl = flat >> 7, tk = flat & 127;
        float4 v4 = *(const float4*)&lt[cl][tk];
        *(float4*)&outf[((size_t)(bq*C_ + ch*64 + cl))*HW_ + n0 + tk] = v4;
      }
    }
  }
}

// ---------------- softmax + deformable bilinear sampling + aggregate --------
// Lane map: lane = (tsub:1)(g:3)(c8:2); XCD-chunk block swizzle for L2 locality.
__global__ __launch_bounds__(256)
void sample_kernel(const bf16* __restrict__ val, const float* __restrict__ off,
                   const float* __restrict__ attnl, const float* __restrict__ anchors,
                   bf16* __restrict__ agg)
{
  const int tid  = threadIdx.x;
  const int lane = tid & 63;
  const int wv   = tid >> 6;
  const int tsub = lane >> 5;
  const int g    = (lane >> 2) & 7;
  const int c8   = lane & 3;
  const int bid  = blockIdx.x;
  const int swz  = (bid & 7) * ((NTOK/8) >> 3) + (bid >> 3);  // 3200 % 8 == 0
  const int t    = swz * 8 + wv * 2 + tsub;
  const int b    = t / HW_;

  const float2 anc = *(const float2*)(anchors + (size_t)t*2);
  const float ax = anc.x * W_ - 0.5f;
  const float ay = anc.y * H_ - 0.5f;

  const float4 l0 = *(const float4*)(attnl + (size_t)t*64 + g*8);
  const float4 l1 = *(const float4*)(attnl + (size_t)t*64 + g*8 + 4);
  float l[8] = {l0.x, l0.y, l0.z, l0.w, l1.x, l1.y, l1.z, l1.w};
  float mx = l[0];
#pragma unroll
  for (int p = 1; p < 8; ++p) mx = fmaxf(mx, l[p]);
  float s = 0.f;
#pragma unroll
  for (int p = 0; p < 8; ++p) { l[p] = __expf(l[p] - mx); s += l[p]; }
  const float inv = 1.f / s;

  const float4* opv = (const float4*)(off + (size_t)t*128 + g*16);
  const float4 o0 = opv[0], o1 = opv[1], o2 = opv[2], o3 = opv[3];
  const float ox[8] = {o0.x, o0.z, o1.x, o1.z, o2.x, o2.z, o3.x, o3.z};
  const float oy[8] = {o0.y, o0.w, o1.y, o1.w, o2.y, o2.w, o3.y, o3.w};

  const bf16* vb = val + ((size_t)b*HW_)*256 + g*32 + c8*8;

  float a[8] = {};
#pragma unroll
  for (int p = 0; p < 8; ++p) {
    const float px = ax + ox[p], py = ay + oy[p];
    const float x0f = floorf(px), y0f = floorf(py);
    const int x0 = (int)x0f, y0 = (int)y0f;
    const float wx1 = px - x0f, wx0 = 1.f - wx1;
    const float wy1 = py - y0f, wy0 = 1.f - wy1;
    const float ap = l[p] * inv;
    float w00 = ap*wx0*wy0, w10 = ap*wx1*wy0, w01 = ap*wx0*wy1, w11 = ap*wx1*wy1;
    const bool vx0 = (unsigned)x0 < W_, vx1 = (unsigned)(x0+1) < W_;
    const bool vy0 = (unsigned)y0 < H_, vy1 = (unsigned)(y0+1) < H_;
    w00 = (vx0 && vy0) ? w00 : 0.f;  w10 = (vx1 && vy0) ? w10 : 0.f;
    w01 = (vx0 && vy1) ? w01 : 0.f;  w11 = (vx1 && vy1) ? w11 : 0.f;
    const int xc0 = min(max(x0, 0), W_-1),   xc1 = min(max(x0+1, 0), W_-1);
    const int yc0 = min(max(y0, 0), H_-1),   yc1 = min(max(y0+1, 0), H_-1);
    const bf16x8 v00 = *(const bf16x8*)(vb + (size_t)(yc0*W_ + xc0)*256);
    const bf16x8 v10 = *(const bf16x8*)(vb + (size_t)(yc0*W_ + xc1)*256);
    const bf16x8 v01 = *(const bf16x8*)(vb + (size_t)(yc1*W_ + xc0)*256);
    const bf16x8 v11 = *(const bf16x8*)(vb + (size_t)(yc1*W_ + xc1)*256);
#pragma unroll
    for (int c = 0; c < 8; ++c)
      a[c] += w00*(float)v00[c] + w10*(float)v10[c]
            + w01*(float)v01[c] + w11*(float)v11[c];
  }
  bf16 r[8];
#pragma unroll
  for (int c = 0; c < 8; ++c) r[c] = (bf16)a[c];
  *(bf16x8*)(agg + (size_t)t*256 + g*32 + c8*8) = *(bf16x8*)r;
}

// ---------------- host-side orchestration -----------------------------------
extern "C" void kernel_launch(void* const* d_in, const int* in_sizes, int n_in,
                              void* d_out, int out_size, void* d_ws, size_t ws_size,
                              hipStream_t stream)
{
  const float* feats   = (const float*)d_in[0];
  const float* featsp  = (const float*)d_in[1];
  const float* anchors = (const float*)d_in[2];
  const float* value_W = (const float*)d_in[3];
  const float* value_b = (const float*)d_in[4];
  const float* off_W   = (const float*)d_in[5];
  const float* off_b   = (const float*)d_in[6];
  const float* attn_W  = (const float*)d_in[7];
  const float* attn_b  = (const float*)d_in[8];
  const float* out_W   = (const float*)d_in[9];
  const float* out_b   = (const float*)d_in[10];
  const float* ln1_g   = (const float*)d_in[11];
  const float* ln1_b   = (const float*)d_in[12];
  const float* ln2_g   = (const float*)d_in[13];
  const float* ln2_b   = (const float*)d_in[14];
  const float* w1      = (const float*)d_in[15];
  const float* b1      = (const float*)d_in[16];
  const float* w2      = (const float*)d_in[17];
  const float* b2      = (const float*)d_in[18];
  float* out = (float*)d_out;

  char* ws = (char*)d_ws;
  size_t cur = 0;
  auto alloc = [&](size_t bytes) -> char* {
    char* p = ws + cur;
    cur += (bytes + 255) & ~(size_t)255;
    return p;
  };
  bf16*  wqkv  = (bf16*) alloc((size_t)NQKVP*256*2);
  bf16*  woutt = (bf16*) alloc((size_t)256*256*2);
  bf16*  w1b   = (bf16*) alloc((size_t)512*256*2);
  bf16*  w2b   = (bf16*) alloc((size_t)256*512*2);
  float* bqkv  = (float*)alloc((size_t)NQKVP*4);
  bf16*  qb    = (bf16*) alloc((size_t)NTOK*256*2);   // live until gemm_ln (residual)
  bf16*  valb  = (bf16*) alloc((size_t)NTOK*256*2);
  float* offv  = (float*)alloc((size_t)NTOK*128*4);
  float* attnl = (float*)alloc((size_t)NTOK*64*4);
  bf16*  aggb  = (bf16*) alloc((size_t)NTOK*256*2);
  bf16*  y1b   = (bf16*) alloc((size_t)NTOK*256*2);
  bf16*  hb    = (bf16*) alloc((size_t)NTOK*512*2);

  prep_weights<<<(NQKVP*256 + 256*256 + 512*256 + 256*512 + NQKVP + 255)/256, 256, 0, stream>>>(
      value_W, value_b, off_W, off_b, attn_W, attn_b, out_W, w1, w2,
      wqkv, bqkv, woutt, w1b, w2b);

  qprep_kernel<<<dim3(HW_/64, C_/64, B_), 256, 0, stream>>>(feats, featsp, qb);

  gemm_kernel<0, 256><<<dim3(NTOK/128, NQKVP/128), 256, 0, stream>>>(
      qb, wqkv, bqkv, valb, offv, attnl);

  sample_kernel<<<NTOK/8, 256, 0, stream>>>(valb, offv, attnl, anchors, aggb);

  gemm_ln_kernel<256, false><<<NTOK/128, 512, 0, stream>>>(
      aggb, woutt, out_b, qb, ln1_g, ln1_b, y1b, nullptr);

  gemm_kernel<2, 256><<<dim3(NTOK/128, 512/128), 256, 0, stream>>>(
      y1b, w1b, b1, hb, nullptr, nullptr);

  gemm_ln_kernel<512, true><<<NTOK/128, 512, 0, stream>>>(
      hb, w2b, b2, y1b, ln2_g, ln2_b, nullptr, out);
}

// Round 6
// 145.286 us; speedup vs baseline: 2.2152x; 1.0014x over previous
//
#include <hip/hip_runtime.h>
#include <hip/hip_bf16.h>
#include <math.h>
#include <stdint.h>

#define B_ 2
#define C_ 256
#define H_ 80
#define W_ 160
#define HW_ (H_*W_)      // 12800
#define NTOK (B_*HW_)    // 25600
#define G_ 8
#define P_ 8
#define NQKV 448         // 256 val + 128 off + 64 attn (padded to 512 for tiles)
#define NQKVP 512

typedef __bf16 bf16;
typedef __attribute__((ext_vector_type(8))) __bf16 bf16x8;
typedef __attribute__((ext_vector_type(4))) float f32x4;

__device__ __forceinline__ void gload_lds16(const void* g, void* l) {
  __builtin_amdgcn_global_load_lds(
      (__attribute__((address_space(1))) void*)g,
      (__attribute__((address_space(3))) void*)l,
      16, 0, 0);
}

// ---------------- weight prep: transpose to [N][K] bf16, concat+pad qkv -----
__global__ __launch_bounds__(256)
void prep_weights(const float* __restrict__ vW, const float* __restrict__ vb,
                  const float* __restrict__ oW, const float* __restrict__ ob,
                  const float* __restrict__ aW, const float* __restrict__ ab,
                  const float* __restrict__ outW,
                  const float* __restrict__ w1, const float* __restrict__ w2,
                  bf16* __restrict__ wqkv, float* __restrict__ bqkv,
                  bf16* __restrict__ woutt, bf16* __restrict__ w1b, bf16* __restrict__ w2b)
{
  int i = blockIdx.x * 256 + threadIdx.x;
  if (i < NQKVP*256) {                      // wqkv_t[n][k], zero-padded rows
    int nn = i >> 8, k = i & 255;
    float w;
    if (nn < 256)      w = vW[k*256 + nn];
    else if (nn < 384) w = oW[k*128 + (nn-256)];
    else if (nn < 448) w = aW[k*64  + (nn-384)];
    else               w = 0.f;
    wqkv[i] = (bf16)w;
  }
  int j = i - NQKVP*256;
  if (j >= 0 && j < 256*256) {              // outW_t[n][k]
    int nn = j >> 8, k = j & 255;
    woutt[j] = (bf16)outW[k*256 + nn];
  }
  int j2 = i - (NQKVP*256 + 256*256);
  if (j2 >= 0 && j2 < 512*256) w1b[j2] = (bf16)w1[j2];   // already [N][K]
  int j3 = i - (NQKVP*256 + 256*256 + 512*256);
  if (j3 >= 0 && j3 < 256*512) w2b[j3] = (bf16)w2[j3];   // already [N][K]
  int j4 = i - (NQKVP*256 + 256*256 + 512*256 + 256*512);
  if (j4 >= 0 && j4 < NQKVP) {
    float bv;
    if (j4 < 256)      bv = vb[j4];
    else if (j4 < 384) bv = ob[j4-256];
    else if (j4 < 448) bv = ab[j4-384];
    else               bv = 0.f;
    bqkv[j4] = bv;
  }
}

// ---------------- q = (feats+feats_pos) transposed NCHW -> (tok, C) bf16 ----
__global__ __launch_bounds__(256)
void qprep_kernel(const float* __restrict__ f, const float* __restrict__ fp,
                  bf16* __restrict__ qb)
{
  __shared__ float lt[64][65];
  const int tid = threadIdx.x;
  const int n0 = blockIdx.x * 64;   // token tile
  const int c0 = blockIdx.y * 64;   // channel tile
  const int b  = blockIdx.z;
#pragma unroll
  for (int i = 0; i < 16; ++i) {
    int cl = i*4 + (tid >> 6), nl = tid & 63;
    size_t gi = ((size_t)(b*C_ + c0 + cl))*HW_ + n0 + nl;
    lt[cl][nl] = f[gi] + fp[gi];
  }
  __syncthreads();
#pragma unroll
  for (int i = 0; i < 16; ++i) {
    int nl = i*4 + (tid >> 6), cl = tid & 63;
    size_t qi = ((size_t)(b*HW_ + n0 + nl))*C_ + c0 + cl;
    qb[qi] = (bf16)lt[cl][nl];
  }
}

// ---------------- bf16 MFMA GEMM, 128x128 tile, BK=64, XOR-swizzled LDS -----
// EPI 0: qkv  -> val bf16 [b][g][HW][32] / off f32 / attn-logit f32
// EPI 2: ffn1 -> h = bf16(silu(acc+bias))
template<int EPI, int KTOT>
__global__ __launch_bounds__(256)
void gemm_kernel(const bf16* __restrict__ A, const bf16* __restrict__ Bt,
                 const float* __restrict__ bias,
                 void* __restrict__ out0, float* __restrict__ out1,
                 float* __restrict__ out2)
{
  __shared__ bf16 lA[128*64];   // 16 KB, [row][BK] with chunk-XOR swizzle
  __shared__ bf16 lB[128*64];   // 16 KB
  const int tid  = threadIdx.x;
  const int wave = tid >> 6, lane = tid & 63;
  const int m0 = blockIdx.x * 128, n0 = blockIdx.y * 128;
  const int wm = wave >> 1, wn = wave & 1;     // 2x2 wave grid, 64x64 each
  const int fr = lane & 15;
  const int fq = lane >> 4;
  f32x4 acc[4][4] = {};

  for (int kc = 0; kc < KTOT/64; ++kc) {
    if (kc) __syncthreads();
#pragma unroll
    for (int it = 0; it < 4; ++it) {
      int chunk = it*256 + tid;          // 16B-chunk index in 128x64 tile
      int row = chunk >> 3, cb = chunk & 7;
      int ksw = ((cb ^ (row & 7)) << 3); // swizzled k-element offset
      gload_lds16(A  + (size_t)(m0+row)*KTOT + kc*64 + ksw,
                  (char*)lA + it*4096 + wave*1024);
      gload_lds16(Bt + (size_t)(n0+row)*KTOT + kc*64 + ksw,
                  (char*)lB + it*4096 + wave*1024);
    }
    __syncthreads();
#pragma unroll
    for (int ks = 0; ks < 2; ++ks) {
      bf16x8 af[4], bg[4];
#pragma unroll
      for (int i = 0; i < 4; ++i) {
        int ar = wm*64 + i*16 + fr;
        af[i] = *(const bf16x8*)&lA[ar*64 + (((ks*4 + fq) ^ (ar & 7)) << 3)];
        int br = wn*64 + i*16 + fr;
        bg[i] = *(const bf16x8*)&lB[br*64 + (((ks*4 + fq) ^ (br & 7)) << 3)];
      }
#pragma unroll
      for (int mi = 0; mi < 4; ++mi)
#pragma unroll
        for (int ni = 0; ni < 4; ++ni)
          acc[mi][ni] = __builtin_amdgcn_mfma_f32_16x16x32_bf16(af[mi], bg[ni], acc[mi][ni], 0, 0, 0);
    }
  }

#pragma unroll
  for (int mi = 0; mi < 4; ++mi)
#pragma unroll
  for (int ni = 0; ni < 4; ++ni)
#pragma unroll
  for (int r = 0; r < 4; ++r) {
    int row = m0 + wm*64 + mi*16 + fq*4 + r;
    int col = n0 + wn*64 + ni*16 + fr;
    float v = acc[mi][ni][r] + bias[col];
    if (EPI == 0) {
      if (col < 256) {
        // val in [b][g][HW][32] layout for group-partitioned sampling
        int g = col >> 5, ch = col & 31;
        int b = row >= HW_ ? 1 : 0;
        int n = row - b*HW_;
        ((bf16*)out0)[(((size_t)(b*G_ + g))*HW_ + n)*32 + ch] = (bf16)v;
      }
      else if (col < 384) out1[(size_t)row*128 + (col-256)] = v;
      else if (col < 448) out2[(size_t)row*64  + (col-384)] = v;
      // cols 448..511 are padding: dropped
    } else {
      float s = v / (1.0f + __expf(-v));
      ((bf16*)out0)[(size_t)row*512 + col] = (bf16)s;
    }
  }
}

// ---------------- GEMM (BM=128, BN=256 full row) + residual + LayerNorm -----
// 512 threads = 8 waves in 2(M)x4(N) grid; y = LN(res + A*Bt^T + bias).
// NCHW_OUT=false: write bf16 token-major (LN1 -> y1b).
// NCHW_OUT=true : write f32 NCHW via LDS retile (LN2 -> final output).
template<int KTOT, bool NCHW_OUT>
__global__ __launch_bounds__(512)
void gemm_ln_kernel(const bf16* __restrict__ A, const bf16* __restrict__ Bt,
                    const float* __restrict__ bias, const bf16* __restrict__ res,
                    const float* __restrict__ gg, const float* __restrict__ bb,
                    bf16* __restrict__ yb, float* __restrict__ outf)
{
  __shared__ __align__(16) char smem[49152];   // lA(16K)+lB(32K); reused as lt
  bf16* lA = (bf16*)smem;
  bf16* lB = (bf16*)(smem + 16384);
  float (*lt)[132] = (float(*)[132])smem;      // 64 ch x 128 tok retile (33.8K)
  __shared__ float2 red[128][4];               // per-row (sum, sumsq) per wn
  const int tid  = threadIdx.x;
  const int wave = tid >> 6, lane = tid & 63;
  const int m0 = blockIdx.x * 128;
  const int wm = wave >> 2, wn = wave & 3;     // 2x4 wave grid, 64x64 each
  const int fr = lane & 15;
  const int fq = lane >> 4;
  f32x4 acc[4][4] = {};

  for (int kc = 0; kc < KTOT/64; ++kc) {
    if (kc) __syncthreads();
#pragma unroll
    for (int it = 0; it < 2; ++it) {         // A: 1024 chunks / 512 thr
      int chunk = it*512 + tid;
      int row = chunk >> 3, cb = chunk & 7;
      int ksw = ((cb ^ (row & 7)) << 3);
      gload_lds16(A + (size_t)(m0+row)*KTOT + kc*64 + ksw,
                  (char*)lA + it*8192 + wave*1024);
    }
#pragma unroll
    for (int it = 0; it < 4; ++it) {         // B: 2048 chunks / 512 thr
      int chunk = it*512 + tid;
      int row = chunk >> 3, cb = chunk & 7;
      int ksw = ((cb ^ (row & 7)) << 3);
      gload_lds16(Bt + (size_t)row*KTOT + kc*64 + ksw,
                  (char*)lB + it*8192 + wave*1024);
    }
    __syncthreads();
#pragma unroll
    for (int ks = 0; ks < 2; ++ks) {
      bf16x8 af[4], bg[4];
#pragma unroll
      for (int i = 0; i < 4; ++i) {
        int ar = wm*64 + i*16 + fr;
        af[i] = *(const bf16x8*)&lA[ar*64 + (((ks*4 + fq) ^ (ar & 7)) << 3)];
        int br = wn*64 + i*16 + fr;
        bg[i] = *(const bf16x8*)&lB[br*64 + (((ks*4 + fq) ^ (br & 7)) << 3)];
      }
#pragma unroll
      for (int mi = 0; mi < 4; ++mi)
#pragma unroll
        for (int ni = 0; ni < 4; ++ni)
          acc[mi][ni] = __builtin_amdgcn_mfma_f32_16x16x32_bf16(af[mi], bg[ni], acc[mi][ni], 0, 0, 0);
    }
  }

  // v = acc + bias + res; per-row LN stats via 16-lane reduce + LDS combine
  float gcol[4], bcol[4];
#pragma unroll
  for (int ni = 0; ni < 4; ++ni) {
    int col = wn*64 + ni*16 + fr;
    gcol[ni] = gg[col]; bcol[ni] = bb[col];
  }
#pragma unroll
  for (int mi = 0; mi < 4; ++mi)
#pragma unroll
  for (int r = 0; r < 4; ++r) {
    int rowl = wm*64 + mi*16 + fq*4 + r;
    size_t rowg = (size_t)(m0 + rowl);
    float s = 0.f, q = 0.f;
#pragma unroll
    for (int ni = 0; ni < 4; ++ni) {
      int col = wn*64 + ni*16 + fr;
      float v = acc[mi][ni][r] + bias[col] + (float)res[rowg*256 + col];
      acc[mi][ni][r] = v;
      s += v; q += v*v;
    }
#pragma unroll
    for (int o = 1; o < 16; o <<= 1) { s += __shfl_xor(s, o, 64); q += __shfl_xor(q, o, 64); }
    if (fr == 0) red[rowl][wn] = make_float2(s, q);
  }
  __syncthreads();
#pragma unroll
  for (int mi = 0; mi < 4; ++mi)
#pragma unroll
  for (int r = 0; r < 4; ++r) {
    int rowl = wm*64 + mi*16 + fq*4 + r;
    float s = 0.f, q = 0.f;
#pragma unroll
    for (int k = 0; k < 4; ++k) { float2 p = red[rowl][k]; s += p.x; q += p.y; }
    const float mean = s * (1.f/256.f);
    const float var  = q * (1.f/256.f) - mean*mean;
    const float rs   = rsqrtf(var + 1e-5f);
#pragma unroll
    for (int ni = 0; ni < 4; ++ni)
      acc[mi][ni][r] = (acc[mi][ni][r] - mean)*rs*gcol[ni] + bcol[ni];
  }

  if constexpr (!NCHW_OUT) {
#pragma unroll
    for (int mi = 0; mi < 4; ++mi)
#pragma unroll
    for (int ni = 0; ni < 4; ++ni)
#pragma unroll
    for (int r = 0; r < 4; ++r) {
      size_t rowg = (size_t)(m0 + wm*64 + mi*16 + fq*4 + r);
      int col = wn*64 + ni*16 + fr;
      yb[rowg*256 + col] = (bf16)acc[mi][ni][r];
    }
  } else {
    // retile through LDS: 4 chunks of 64 channels, coalesced NCHW f32 writes
    const int bq = m0 / HW_;
    const int n0 = m0 % HW_;
    __syncthreads();   // lA/lB fully consumed; safe to overlay lt
#pragma unroll
    for (int ch = 0; ch < 4; ++ch) {
      if (ch) __syncthreads();
      if (wn == ch) {
#pragma unroll
        for (int mi = 0; mi < 4; ++mi)
#pragma unroll
        for (int ni = 0; ni < 4; ++ni)
#pragma unroll
        for (int r = 0; r < 4; ++r)
          lt[ni*16 + fr][wm*64 + mi*16 + fq*4 + r] = acc[mi][ni][r];
      }
      __syncthreads();
#pragma unroll
      for (int j = 0; j < 4; ++j) {
        int flat = j*2048 + tid*4;
        int cl = flat >> 7, tk = flat & 127;
        float4 v4 = *(const float4*)&lt[cl][tk];
        *(float4*)&outf[((size_t)(bq*C_ + ch*64 + cl))*HW_ + n0 + tk] = v4;
      }
    }
  }
}

// ---------------- softmax + deformable bilinear sampling + aggregate --------
// Group-partitioned: block = (g, 64-token chunk); g = bid%8 pins each group's
// 3.2 MB val slice [b][g][HW][32] to one XCD's L2 (round-robin dispatch).
// Lane map: lane = (tok:4)(c8:2); 4 lanes/token each own 8 channels.
__global__ __launch_bounds__(256)
void sample_kernel(const bf16* __restrict__ val, const float* __restrict__ off,
                   const float* __restrict__ attnl, const float* __restrict__ anchors,
                   bf16* __restrict__ agg)
{
  const int tid  = threadIdx.x;
  const int lane = tid & 63;
  const int wv   = tid >> 6;
  const int c8   = lane & 3;
  const int bid  = blockIdx.x;
  const int g    = bid & 7;           // == XCD id under round-robin dispatch
  const int chunk= bid >> 3;          // 0..399
  const int t    = chunk*64 + wv*16 + (lane >> 2);
  const int b    = (t >= HW_) ? 1 : 0;

  const float2 anc = *(const float2*)(anchors + (size_t)t*2);
  const float ax = anc.x * W_ - 0.5f;
  const float ay = anc.y * H_ - 0.5f;

  const float4 l0 = *(const float4*)(attnl + (size_t)t*64 + g*8);
  const float4 l1 = *(const float4*)(attnl + (size_t)t*64 + g*8 + 4);
  float l[8] = {l0.x, l0.y, l0.z, l0.w, l1.x, l1.y, l1.z, l1.w};
  float mx = l[0];
#pragma unroll
  for (int p = 1; p < 8; ++p) mx = fmaxf(mx, l[p]);
  float s = 0.f;
#pragma unroll
  for (int p = 0; p < 8; ++p) { l[p] = __expf(l[p] - mx); s += l[p]; }
  const float inv = 1.f / s;

  const float4* opv = (const float4*)(off + (size_t)t*128 + g*16);
  const float4 o0 = opv[0], o1 = opv[1], o2 = opv[2], o3 = opv[3];
  const float ox[8] = {o0.x, o0.z, o1.x, o1.z, o2.x, o2.z, o3.x, o3.z};
  const float oy[8] = {o0.y, o0.w, o1.y, o1.w, o2.y, o2.w, o3.y, o3.w};

  const bf16* vb = val + ((size_t)(b*G_ + g)*HW_)*32 + c8*8;

  float a[8] = {};
#pragma unroll
  for (int p = 0; p < 8; ++p) {
    const float px = ax + ox[p], py = ay + oy[p];
    const float x0f = floorf(px), y0f = floorf(py);
    const int x0 = (int)x0f, y0 = (int)y0f;
    const float wx1 = px - x0f, wx0 = 1.f - wx1;
    const float wy1 = py - y0f, wy0 = 1.f - wy1;
    const float ap = l[p] * inv;
    float w00 = ap*wx0*wy0, w10 = ap*wx1*wy0, w01 = ap*wx0*wy1, w11 = ap*wx1*wy1;
    const bool vx0 = (unsigned)x0 < W_, vx1 = (unsigned)(x0+1) < W_;
    const bool vy0 = (unsigned)y0 < H_, vy1 = (unsigned)(y0+1) < H_;
    w00 = (vx0 && vy0) ? w00 : 0.f;  w10 = (vx1 && vy0) ? w10 : 0.f;
    w01 = (vx0 && vy1) ? w01 : 0.f;  w11 = (vx1 && vy1) ? w11 : 0.f;
    const int xc0 = min(max(x0, 0), W_-1),   xc1 = min(max(x0+1, 0), W_-1);
    const int yc0 = min(max(y0, 0), H_-1),   yc1 = min(max(y0+1, 0), H_-1);
    const bf16x8 v00 = *(const bf16x8*)(vb + (size_t)(yc0*W_ + xc0)*32);
    const bf16x8 v10 = *(const bf16x8*)(vb + (size_t)(yc0*W_ + xc1)*32);
    const bf16x8 v01 = *(const bf16x8*)(vb + (size_t)(yc1*W_ + xc0)*32);
    const bf16x8 v11 = *(const bf16x8*)(vb + (size_t)(yc1*W_ + xc1)*32);
#pragma unroll
    for (int c = 0; c < 8; ++c)
      a[c] += w00*(float)v00[c] + w10*(float)v10[c]
            + w01*(float)v01[c] + w11*(float)v11[c];
  }
  bf16 r[8];
#pragma unroll
  for (int c = 0; c < 8; ++c) r[c] = (bf16)a[c];
  *(bf16x8*)(agg + (size_t)t*256 + g*32 + c8*8) = *(bf16x8*)r;
}

// ---------------- host-side orchestration -----------------------------------
extern "C" void kernel_launch(void* const* d_in, const int* in_sizes, int n_in,
                              void* d_out, int out_size, void* d_ws, size_t ws_size,
                              hipStream_t stream)
{
  const float* feats   = (const float*)d_in[0];
  const float* featsp  = (const float*)d_in[1];
  const float* anchors = (const float*)d_in[2];
  const float* value_W = (const float*)d_in[3];
  const float* value_b = (const float*)d_in[4];
  const float* off_W   = (const float*)d_in[5];
  const float* off_b   = (const float*)d_in[6];
  const float* attn_W  = (const float*)d_in[7];
  const float* attn_b  = (const float*)d_in[8];
  const float* out_W   = (const float*)d_in[9];
  const float* out_b   = (const float*)d_in[10];
  const float* ln1_g   = (const float*)d_in[11];
  const float* ln1_b   = (const float*)d_in[12];
  const float* ln2_g   = (const float*)d_in[13];
  const float* ln2_b   = (const float*)d_in[14];
  const float* w1      = (const float*)d_in[15];
  const float* b1      = (const float*)d_in[16];
  const float* w2      = (const float*)d_in[17];
  const float* b2      = (const float*)d_in[18];
  float* out = (float*)d_out;

  char* ws = (char*)d_ws;
  size_t cur = 0;
  auto alloc = [&](size_t bytes) -> char* {
    char* p = ws + cur;
    cur += (bytes + 255) & ~(size_t)255;
    return p;
  };
  bf16*  wqkv  = (bf16*) alloc((size_t)NQKVP*256*2);
  bf16*  woutt = (bf16*) alloc((size_t)256*256*2);
  bf16*  w1b   = (bf16*) alloc((size_t)512*256*2);
  bf16*  w2b   = (bf16*) alloc((size_t)256*512*2);
  float* bqkv  = (float*)alloc((size_t)NQKVP*4);
  bf16*  qb    = (bf16*) alloc((size_t)NTOK*256*2);   // live until gemm_ln (residual)
  bf16*  valb  = (bf16*) alloc((size_t)NTOK*256*2);   // [b][g][HW][32]
  float* offv  = (float*)alloc((size_t)NTOK*128*4);
  float* attnl = (float*)alloc((size_t)NTOK*64*4);
  bf16*  aggb  = (bf16*) alloc((size_t)NTOK*256*2);
  bf16*  y1b   = (bf16*) alloc((size_t)NTOK*256*2);
  bf16*  hb    = (bf16*) alloc((size_t)NTOK*512*2);

  prep_weights<<<(NQKVP*256 + 256*256 + 512*256 + 256*512 + NQKVP + 255)/256, 256, 0, stream>>>(
      value_W, value_b, off_W, off_b, attn_W, attn_b, out_W, w1, w2,
      wqkv, bqkv, woutt, w1b, w2b);

  qprep_kernel<<<dim3(HW_/64, C_/64, B_), 256, 0, stream>>>(feats, featsp, qb);

  gemm_kernel<0, 256><<<dim3(NTOK/128, NQKVP/128), 256, 0, stream>>>(
      qb, wqkv, bqkv, valb, offv, attnl);

  sample_kernel<<<NTOK/8, 256, 0, stream>>>(valb, offv, attnl, anchors, aggb);

  gemm_ln_kernel<256, false><<<NTOK/128, 512, 0, stream>>>(
      aggb, woutt, out_b, qb, ln1_g, ln1_b, y1b, nullptr);

  gemm_kernel<2, 256><<<dim3(NTOK/128, 512/128), 256, 0, stream>>>(
      y1b, w1b, b1, hb, nullptr, nullptr);

  gemm_ln_kernel<512, true><<<NTOK/128, 512, 0, stream>>>(
      hb, w2b, b2, y1b, ln2_g, ln2_b, nullptr, out);
}

// Round 7
// 141.540 us; speedup vs baseline: 2.2738x; 1.0265x over previous
//
#include <hip/hip_runtime.h>
#include <hip/hip_bf16.h>
#include <math.h>
#include <stdint.h>

#define B_ 2
#define C_ 256
#define H_ 80
#define W_ 160
#define HW_ (H_*W_)      // 12800
#define NTOK (B_*HW_)    // 25600
#define G_ 8
#define P_ 8
#define NQKV 448         // 256 val + 128 off + 64 attn (padded to 512 for tiles)
#define NQKVP 512

typedef __bf16 bf16;
typedef __attribute__((ext_vector_type(8))) __bf16 bf16x8;
typedef __attribute__((ext_vector_type(4))) float f32x4;

__device__ __forceinline__ void gload_lds16(const void* g, void* l) {
  __builtin_amdgcn_global_load_lds(
      (__attribute__((address_space(1))) void*)g,
      (__attribute__((address_space(3))) void*)l,
      16, 0, 0);
}

// ---------------- weight prep: transpose to [N][K] bf16, concat+pad qkv -----
__global__ __launch_bounds__(256)
void prep_weights(const float* __restrict__ vW, const float* __restrict__ vb,
                  const float* __restrict__ oW, const float* __restrict__ ob,
                  const float* __restrict__ aW, const float* __restrict__ ab,
                  const float* __restrict__ outW,
                  const float* __restrict__ w1, const float* __restrict__ w2,
                  bf16* __restrict__ wqkv, float* __restrict__ bqkv,
                  bf16* __restrict__ woutt, bf16* __restrict__ w1b, bf16* __restrict__ w2b)
{
  int i = blockIdx.x * 256 + threadIdx.x;
  if (i < NQKVP*256) {                      // wqkv_t[n][k], zero-padded rows
    int nn = i >> 8, k = i & 255;
    float w;
    if (nn < 256)      w = vW[k*256 + nn];
    else if (nn < 384) w = oW[k*128 + (nn-256)];
    else if (nn < 448) w = aW[k*64  + (nn-384)];
    else               w = 0.f;
    wqkv[i] = (bf16)w;
  }
  int j = i - NQKVP*256;
  if (j >= 0 && j < 256*256) {              // outW_t[n][k]
    int nn = j >> 8, k = j & 255;
    woutt[j] = (bf16)outW[k*256 + nn];
  }
  int j2 = i - (NQKVP*256 + 256*256);
  if (j2 >= 0 && j2 < 512*256) w1b[j2] = (bf16)w1[j2];   // already [N][K]
  int j3 = i - (NQKVP*256 + 256*256 + 512*256);
  if (j3 >= 0 && j3 < 256*512) w2b[j3] = (bf16)w2[j3];   // already [N][K]
  int j4 = i - (NQKVP*256 + 256*256 + 512*256 + 256*512);
  if (j4 >= 0 && j4 < NQKVP) {
    float bv;
    if (j4 < 256)      bv = vb[j4];
    else if (j4 < 384) bv = ob[j4-256];
    else if (j4 < 448) bv = ab[j4-384];
    else               bv = 0.f;
    bqkv[j4] = bv;
  }
}

// ---------------- q = (feats+feats_pos) transposed NCHW -> (tok, C) bf16 ----
__global__ __launch_bounds__(256)
void qprep_kernel(const float* __restrict__ f, const float* __restrict__ fp,
                  bf16* __restrict__ qb)
{
  __shared__ float lt[64][65];
  const int tid = threadIdx.x;
  const int n0 = blockIdx.x * 64;   // token tile
  const int c0 = blockIdx.y * 64;   // channel tile
  const int b  = blockIdx.z;
#pragma unroll
  for (int i = 0; i < 16; ++i) {
    int cl = i*4 + (tid >> 6), nl = tid & 63;
    size_t gi = ((size_t)(b*C_ + c0 + cl))*HW_ + n0 + nl;
    lt[cl][nl] = f[gi] + fp[gi];
  }
  __syncthreads();
#pragma unroll
  for (int i = 0; i < 16; ++i) {
    int nl = i*4 + (tid >> 6), cl = tid & 63;
    size_t qi = ((size_t)(b*HW_ + n0 + nl))*C_ + c0 + cl;
    qb[qi] = (bf16)lt[cl][nl];
  }
}

// ---------------- bf16 MFMA GEMM, 128x128 tile, BK=64, XOR-swizzled LDS -----
// EPI 0: qkv  -> val bf16 [b][g][HW][32] / off f32 / attn-logit f32
template<int EPI, int KTOT>
__global__ __launch_bounds__(256)
void gemm_kernel(const bf16* __restrict__ A, const bf16* __restrict__ Bt,
                 const float* __restrict__ bias,
                 void* __restrict__ out0, float* __restrict__ out1,
                 float* __restrict__ out2)
{
  __shared__ bf16 lA[128*64];   // 16 KB, [row][BK] with chunk-XOR swizzle
  __shared__ bf16 lB[128*64];   // 16 KB
  const int tid  = threadIdx.x;
  const int wave = tid >> 6, lane = tid & 63;
  const int m0 = blockIdx.x * 128, n0 = blockIdx.y * 128;
  const int wm = wave >> 1, wn = wave & 1;     // 2x2 wave grid, 64x64 each
  const int fr = lane & 15;
  const int fq = lane >> 4;
  f32x4 acc[4][4] = {};

  for (int kc = 0; kc < KTOT/64; ++kc) {
    if (kc) __syncthreads();
#pragma unroll
    for (int it = 0; it < 4; ++it) {
      int chunk = it*256 + tid;          // 16B-chunk index in 128x64 tile
      int row = chunk >> 3, cb = chunk & 7;
      int ksw = ((cb ^ (row & 7)) << 3); // swizzled k-element offset
      gload_lds16(A  + (size_t)(m0+row)*KTOT + kc*64 + ksw,
                  (char*)lA + it*4096 + wave*1024);
      gload_lds16(Bt + (size_t)(n0+row)*KTOT + kc*64 + ksw,
                  (char*)lB + it*4096 + wave*1024);
    }
    __syncthreads();
#pragma unroll
    for (int ks = 0; ks < 2; ++ks) {
      bf16x8 af[4], bg[4];
#pragma unroll
      for (int i = 0; i < 4; ++i) {
        int ar = wm*64 + i*16 + fr;
        af[i] = *(const bf16x8*)&lA[ar*64 + (((ks*4 + fq) ^ (ar & 7)) << 3)];
        int br = wn*64 + i*16 + fr;
        bg[i] = *(const bf16x8*)&lB[br*64 + (((ks*4 + fq) ^ (br & 7)) << 3)];
      }
#pragma unroll
      for (int mi = 0; mi < 4; ++mi)
#pragma unroll
        for (int ni = 0; ni < 4; ++ni)
          acc[mi][ni] = __builtin_amdgcn_mfma_f32_16x16x32_bf16(af[mi], bg[ni], acc[mi][ni], 0, 0, 0);
    }
  }

#pragma unroll
  for (int mi = 0; mi < 4; ++mi)
#pragma unroll
  for (int ni = 0; ni < 4; ++ni)
#pragma unroll
  for (int r = 0; r < 4; ++r) {
    int row = m0 + wm*64 + mi*16 + fq*4 + r;
    int col = n0 + wn*64 + ni*16 + fr;
    float v = acc[mi][ni][r] + bias[col];
    if (EPI == 0) {
      if (col < 256) {
        // val in [b][g][HW][32] layout for sampling (2 corners per cache line)
        int g = col >> 5, ch = col & 31;
        int b = row >= HW_ ? 1 : 0;
        int n = row - b*HW_;
        ((bf16*)out0)[(((size_t)(b*G_ + g))*HW_ + n)*32 + ch] = (bf16)v;
      }
      else if (col < 384) out1[(size_t)row*128 + (col-256)] = v;
      else if (col < 448) out2[(size_t)row*64  + (col-384)] = v;
      // cols 448..511 are padding: dropped
    }
  }
}

// ---------------- out-proj GEMM (BM=128, BN=256) + residual + LayerNorm1 ----
__global__ __launch_bounds__(512)
void gemm_ln_kernel(const bf16* __restrict__ A, const bf16* __restrict__ Bt,
                    const float* __restrict__ bias, const bf16* __restrict__ res,
                    const float* __restrict__ gg, const float* __restrict__ bb,
                    bf16* __restrict__ yb)
{
  __shared__ __align__(16) char smem[49152];   // lA(16K)+lB(32K)
  bf16* lA = (bf16*)smem;
  bf16* lB = (bf16*)(smem + 16384);
  __shared__ float2 red[128][4];               // per-row (sum, sumsq) per wn
  const int tid  = threadIdx.x;
  const int wave = tid >> 6, lane = tid & 63;
  const int m0 = blockIdx.x * 128;
  const int wm = wave >> 2, wn = wave & 3;     // 2x4 wave grid, 64x64 each
  const int fr = lane & 15;
  const int fq = lane >> 4;
  f32x4 acc[4][4] = {};

  for (int kc = 0; kc < 256/64; ++kc) {
    if (kc) __syncthreads();
#pragma unroll
    for (int it = 0; it < 2; ++it) {         // A: 1024 chunks / 512 thr
      int chunk = it*512 + tid;
      int row = chunk >> 3, cb = chunk & 7;
      int ksw = ((cb ^ (row & 7)) << 3);
      gload_lds16(A + (size_t)(m0+row)*256 + kc*64 + ksw,
                  (char*)lA + it*8192 + wave*1024);
    }
#pragma unroll
    for (int it = 0; it < 4; ++it) {         // B: 2048 chunks / 512 thr
      int chunk = it*512 + tid;
      int row = chunk >> 3, cb = chunk & 7;
      int ksw = ((cb ^ (row & 7)) << 3);
      gload_lds16(Bt + (size_t)row*256 + kc*64 + ksw,
                  (char*)lB + it*8192 + wave*1024);
    }
    __syncthreads();
#pragma unroll
    for (int ks = 0; ks < 2; ++ks) {
      bf16x8 af[4], bg[4];
#pragma unroll
      for (int i = 0; i < 4; ++i) {
        int ar = wm*64 + i*16 + fr;
        af[i] = *(const bf16x8*)&lA[ar*64 + (((ks*4 + fq) ^ (ar & 7)) << 3)];
        int br = wn*64 + i*16 + fr;
        bg[i] = *(const bf16x8*)&lB[br*64 + (((ks*4 + fq) ^ (br & 7)) << 3)];
      }
#pragma unroll
      for (int mi = 0; mi < 4; ++mi)
#pragma unroll
        for (int ni = 0; ni < 4; ++ni)
          acc[mi][ni] = __builtin_amdgcn_mfma_f32_16x16x32_bf16(af[mi], bg[ni], acc[mi][ni], 0, 0, 0);
    }
  }

  float gcol[4], bcol[4];
#pragma unroll
  for (int ni = 0; ni < 4; ++ni) {
    int col = wn*64 + ni*16 + fr;
    gcol[ni] = gg[col]; bcol[ni] = bb[col];
  }
#pragma unroll
  for (int mi = 0; mi < 4; ++mi)
#pragma unroll
  for (int r = 0; r < 4; ++r) {
    int rowl = wm*64 + mi*16 + fq*4 + r;
    size_t rowg = (size_t)(m0 + rowl);
    float s = 0.f, q = 0.f;
#pragma unroll
    for (int ni = 0; ni < 4; ++ni) {
      int col = wn*64 + ni*16 + fr;
      float v = acc[mi][ni][r] + bias[col] + (float)res[rowg*256 + col];
      acc[mi][ni][r] = v;
      s += v; q += v*v;
    }
#pragma unroll
    for (int o = 1; o < 16; o <<= 1) { s += __shfl_xor(s, o, 64); q += __shfl_xor(q, o, 64); }
    if (fr == 0) red[rowl][wn] = make_float2(s, q);
  }
  __syncthreads();
#pragma unroll
  for (int mi = 0; mi < 4; ++mi)
#pragma unroll
  for (int r = 0; r < 4; ++r) {
    int rowl = wm*64 + mi*16 + fq*4 + r;
    size_t rowg = (size_t)(m0 + rowl);
    float s = 0.f, q = 0.f;
#pragma unroll
    for (int k = 0; k < 4; ++k) { float2 p = red[rowl][k]; s += p.x; q += p.y; }
    const float mean = s * (1.f/256.f);
    const float var  = q * (1.f/256.f) - mean*mean;
    const float rs   = rsqrtf(var + 1e-5f);
#pragma unroll
    for (int ni = 0; ni < 4; ++ni) {
      int col = wn*64 + ni*16 + fr;
      float y = (acc[mi][ni][r] - mean)*rs*gcol[ni] + bcol[ni];
      yb[rowg*256 + col] = (bf16)y;
    }
  }
}

// ---------------- fused FFN: y1 -> silu(y1@w1^T+b1)@w2^T+b2 + y1 -> LN2 -> NCHW
// Block = 128 tokens, 512 thr / 8 waves. y1 tile resident in LDS (yA);
// h computed in 4 chunks of 128 through hA; x2 accumulated in registers.
__global__ __launch_bounds__(512)
void ffn_kernel(const bf16* __restrict__ y1b, const bf16* __restrict__ w1b,
                const float* __restrict__ b1, const bf16* __restrict__ w2b,
                const float* __restrict__ b2,
                const float* __restrict__ gg, const float* __restrict__ bb,
                float* __restrict__ outf)
{
  __shared__ __align__(16) char smem[131072];  // yA 64K | hA 32K | bst 32K
  bf16* yA  = (bf16*)smem;                     // [128][256] swizzled
  bf16* hA  = (bf16*)(smem + 65536);           // [128][128] swizzled
  bf16* bst = (bf16*)(smem + 98304);           // K-step B staging
  float (*lt)[132] = (float(*)[132])smem;      // overlays yA at epilogue
  __shared__ float2 red[128][4];
  const int tid  = threadIdx.x;
  const int wave = tid >> 6, lane = tid & 63;
  const int m0 = blockIdx.x * 128;
  const int fr = lane & 15, fq = lane >> 4;
  const int wm1 = wave >> 1, wn1 = wave & 1;   // phase1: 4(M)x2(N) of 32x64
  const int wm = wave >> 2,  wn = wave & 3;    // phase2: 2(M)x4(N) of 64x64

  // stage y1 tile once (pre-swizzled source, linear LDS dest)
#pragma unroll
  for (int it = 0; it < 8; ++it) {
    int chunk = it*512 + tid;                  // 4096 chunks = 128 rows x 32
    int row = chunk >> 5, cb = chunk & 31;
    gload_lds16(y1b + (size_t)(m0+row)*256 + ((cb ^ (row&7))<<3),
                (char*)yA + it*8192 + wave*1024);
  }
  f32x4 acc2[4][4] = {};
  __syncthreads();

  for (int nc = 0; nc < 4; ++nc) {
    // ---- phase 1: h_chunk = silu(yA @ w1[nc*128..][:]^T + b1)  (128x128, K=256)
    f32x4 acc1[2][4] = {};
    for (int kc = 0; kc < 4; ++kc) {
#pragma unroll
      for (int it = 0; it < 2; ++it) {         // B: 128x64 = 1024 chunks
        int chunk = it*512 + tid;
        int row = chunk >> 3, cb = chunk & 7;
        gload_lds16(w1b + (size_t)(nc*128+row)*256 + kc*64 + ((cb ^ (row&7))<<3),
                    (char*)bst + it*8192 + wave*1024);
      }
      __syncthreads();
#pragma unroll
      for (int ks = 0; ks < 2; ++ks) {
        bf16x8 af[2], bg[4];
#pragma unroll
        for (int i = 0; i < 2; ++i) {
          int ar = wm1*32 + i*16 + fr;
          af[i] = *(const bf16x8*)&yA[ar*256 + (((kc*8 + ks*4 + fq) ^ (ar&7))<<3)];
        }
#pragma unroll
        for (int i = 0; i < 4; ++i) {
          int br = wn1*64 + i*16 + fr;
          bg[i] = *(const bf16x8*)&bst[br*64 + (((ks*4 + fq) ^ (br&7))<<3)];
        }
#pragma unroll
        for (int mi = 0; mi < 2; ++mi)
#pragma unroll
          for (int ni = 0; ni < 4; ++ni)
            acc1[mi][ni] = __builtin_amdgcn_mfma_f32_16x16x32_bf16(af[mi], bg[ni], acc1[mi][ni], 0,0,0);
      }
      __syncthreads();
    }
    // silu + write h_chunk into hA (swizzled, matches phase-2 A reads)
#pragma unroll
    for (int mi = 0; mi < 2; ++mi)
#pragma unroll
    for (int ni = 0; ni < 4; ++ni)
#pragma unroll
    for (int r = 0; r < 4; ++r) {
      int row = wm1*32 + mi*16 + fq*4 + r;
      int col = wn1*64 + ni*16 + fr;
      float v = acc1[mi][ni][r] + b1[nc*128 + col];
      float s = v / (1.0f + __expf(-v));
      hA[row*128 + (((col>>3) ^ (row&7))<<3) + (col&7)] = (bf16)s;
    }
    __syncthreads();
    // ---- phase 2: acc2 += hA @ w2[:, nc*128..]^T   (128x256, K=128)
    for (int kc = 0; kc < 2; ++kc) {
#pragma unroll
      for (int it = 0; it < 4; ++it) {         // B: 256x64 = 2048 chunks
        int chunk = it*512 + tid;
        int row = chunk >> 3, cb = chunk & 7;
        gload_lds16(w2b + (size_t)row*512 + nc*128 + kc*64 + ((cb ^ (row&7))<<3),
                    (char*)bst + it*8192 + wave*1024);
      }
      __syncthreads();
#pragma unroll
      for (int ks = 0; ks < 2; ++ks) {
        bf16x8 af[4], bg[4];
#pragma unroll
        for (int i = 0; i < 4; ++i) {
          int ar = wm*64 + i*16 + fr;
          af[i] = *(const bf16x8*)&hA[ar*128 + (((kc*8 + ks*4 + fq) ^ (ar&7))<<3)];
        }
#pragma unroll
        for (int i = 0; i < 4; ++i) {
          int br = wn*64 + i*16 + fr;
          bg[i] = *(const bf16x8*)&bst[br*64 + (((ks*4 + fq) ^ (br&7))<<3)];
        }
#pragma unroll
        for (int mi = 0; mi < 4; ++mi)
#pragma unroll
          for (int ni = 0; ni < 4; ++ni)
            acc2[mi][ni] = __builtin_amdgcn_mfma_f32_16x16x32_bf16(af[mi], bg[ni], acc2[mi][ni], 0,0,0);
      }
      __syncthreads();
    }
  }

  // ---- epilogue: + b2 + residual(y1) ; LN2 ; NCHW f32 out
  float gcol[4], bcol[4];
#pragma unroll
  for (int ni = 0; ni < 4; ++ni) {
    int col = wn*64 + ni*16 + fr;
    gcol[ni] = gg[col]; bcol[ni] = bb[col];
  }
#pragma unroll
  for (int mi = 0; mi < 4; ++mi)
#pragma unroll
  for (int r = 0; r < 4; ++r) {
    int rowl = wm*64 + mi*16 + fq*4 + r;
    size_t rowg = (size_t)(m0 + rowl);
    float s = 0.f, q = 0.f;
#pragma unroll
    for (int ni = 0; ni < 4; ++ni) {
      int col = wn*64 + ni*16 + fr;
      float v = acc2[mi][ni][r] + b2[col] + (float)y1b[rowg*256 + col];
      acc2[mi][ni][r] = v;
      s += v; q += v*v;
    }
#pragma unroll
    for (int o = 1; o < 16; o <<= 1) { s += __shfl_xor(s, o, 64); q += __shfl_xor(q, o, 64); }
    if (fr == 0) red[rowl][wn] = make_float2(s, q);
  }
  __syncthreads();
#pragma unroll
  for (int mi = 0; mi < 4; ++mi)
#pragma unroll
  for (int r = 0; r < 4; ++r) {
    int rowl = wm*64 + mi*16 + fq*4 + r;
    float s = 0.f, q = 0.f;
#pragma unroll
    for (int k = 0; k < 4; ++k) { float2 p = red[rowl][k]; s += p.x; q += p.y; }
    const float mean = s * (1.f/256.f);
    const float var  = q * (1.f/256.f) - mean*mean;
    const float rs   = rsqrtf(var + 1e-5f);
#pragma unroll
    for (int ni = 0; ni < 4; ++ni)
      acc2[mi][ni][r] = (acc2[mi][ni][r] - mean)*rs*gcol[ni] + bcol[ni];
  }
  const int bq = m0 / HW_;
  const int n0 = m0 % HW_;
  __syncthreads();   // yA dead (residual came from global); overlay lt
#pragma unroll
  for (int ch = 0; ch < 4; ++ch) {
    if (ch) __syncthreads();
    if (wn == ch) {
#pragma unroll
      for (int mi = 0; mi < 4; ++mi)
#pragma unroll
      for (int ni = 0; ni < 4; ++ni)
#pragma unroll
      for (int r = 0; r < 4; ++r)
        lt[ni*16 + fr][wm*64 + mi*16 + fq*4 + r] = acc2[mi][ni][r];
    }
    __syncthreads();
#pragma unroll
    for (int j = 0; j < 4; ++j) {
      int flat = j*2048 + tid*4;
      int cl = flat >> 7, tk = flat & 127;
      float4 v4 = *(const float4*)&lt[cl][tk];
      *(float4*)&outf[((size_t)(bq*C_ + ch*64 + cl))*HW_ + n0 + tk] = v4;
    }
  }
}

// ---------------- softmax + deformable bilinear sampling + aggregate --------
__global__ __launch_bounds__(256)
void sample_kernel(const bf16* __restrict__ val, const float* __restrict__ off,
                   const float* __restrict__ attnl, const float* __restrict__ anchors,
                   bf16* __restrict__ agg)
{
  const int tid  = threadIdx.x;
  const int lane = tid & 63;
  const int wv   = tid >> 6;
  const int c8   = lane & 3;
  const int bid  = blockIdx.x;
  const int g    = bid & 7;
  const int chunk= bid >> 3;
  const int t    = chunk*64 + wv*16 + (lane >> 2);
  const int b    = (t >= HW_) ? 1 : 0;

  const float2 anc = *(const float2*)(anchors + (size_t)t*2);
  const float ax = anc.x * W_ - 0.5f;
  const float ay = anc.y * H_ - 0.5f;

  const float4 l0 = *(const float4*)(attnl + (size_t)t*64 + g*8);
  const float4 l1 = *(const float4*)(attnl + (size_t)t*64 + g*8 + 4);
  float l[8] = {l0.x, l0.y, l0.z, l0.w, l1.x, l1.y, l1.z, l1.w};
  float mx = l[0];
#pragma unroll
  for (int p = 1; p < 8; ++p) mx = fmaxf(mx, l[p]);
  float s = 0.f;
#pragma unroll
  for (int p = 0; p < 8; ++p) { l[p] = __expf(l[p] - mx); s += l[p]; }
  const float inv = 1.f / s;

  const float4* opv = (const float4*)(off + (size_t)t*128 + g*16);
  const float4 o0 = opv[0], o1 = opv[1], o2 = opv[2], o3 = opv[3];
  const float ox[8] = {o0.x, o0.z, o1.x, o1.z, o2.x, o2.z, o3.x, o3.z};
  const float oy[8] = {o0.y, o0.w, o1.y, o1.w, o2.y, o2.w, o3.y, o3.w};

  const bf16* vb = val + ((size_t)(b*G_ + g)*HW_)*32 + c8*8;

  float a[8] = {};
#pragma unroll
  for (int p = 0; p < 8; ++p) {
    const float px = ax + ox[p], py = ay + oy[p];
    const float x0f = floorf(px), y0f = floorf(py);
    const int x0 = (int)x0f, y0 = (int)y0f;
    const float wx1 = px - x0f, wx0 = 1.f - wx1;
    const float wy1 = py - y0f, wy0 = 1.f - wy1;
    const float ap = l[p] * inv;
    float w00 = ap*wx0*wy0, w10 = ap*wx1*wy0, w01 = ap*wx0*wy1, w11 = ap*wx1*wy1;
    const bool vx0 = (unsigned)x0 < W_, vx1 = (unsigned)(x0+1) < W_;
    const bool vy0 = (unsigned)y0 < H_, vy1 = (unsigned)(y0+1) < H_;
    w00 = (vx0 && vy0) ? w00 : 0.f;  w10 = (vx1 && vy0) ? w10 : 0.f;
    w01 = (vx0 && vy1) ? w01 : 0.f;  w11 = (vx1 && vy1) ? w11 : 0.f;
    const int xc0 = min(max(x0, 0), W_-1),   xc1 = min(max(x0+1, 0), W_-1);
    const int yc0 = min(max(y0, 0), H_-1),   yc1 = min(max(y0+1, 0), H_-1);
    const bf16x8 v00 = *(const bf16x8*)(vb + (size_t)(yc0*W_ + xc0)*32);
    const bf16x8 v10 = *(const bf16x8*)(vb + (size_t)(yc0*W_ + xc1)*32);
    const bf16x8 v01 = *(const bf16x8*)(vb + (size_t)(yc1*W_ + xc0)*32);
    const bf16x8 v11 = *(const bf16x8*)(vb + (size_t)(yc1*W_ + xc1)*32);
#pragma unroll
    for (int c = 0; c < 8; ++c)
      a[c] += w00*(float)v00[c] + w10*(float)v10[c]
            + w01*(float)v01[c] + w11*(float)v11[c];
  }
  bf16 r[8];
#pragma unroll
  for (int c = 0; c < 8; ++c) r[c] = (bf16)a[c];
  *(bf16x8*)(agg + (size_t)t*256 + g*32 + c8*8) = *(bf16x8*)r;
}

// ---------------- host-side orchestration -----------------------------------
extern "C" void kernel_launch(void* const* d_in, const int* in_sizes, int n_in,
                              void* d_out, int out_size, void* d_ws, size_t ws_size,
                              hipStream_t stream)
{
  const float* feats   = (const float*)d_in[0];
  const float* featsp  = (const float*)d_in[1];
  const float* anchors = (const float*)d_in[2];
  const float* value_W = (const float*)d_in[3];
  const float* value_b = (const float*)d_in[4];
  const float* off_W   = (const float*)d_in[5];
  const float* off_b   = (const float*)d_in[6];
  const float* attn_W  = (const float*)d_in[7];
  const float* attn_b  = (const float*)d_in[8];
  const float* out_W   = (const float*)d_in[9];
  const float* out_b   = (const float*)d_in[10];
  const float* ln1_g   = (const float*)d_in[11];
  const float* ln1_b   = (const float*)d_in[12];
  const float* ln2_g   = (const float*)d_in[13];
  const float* ln2_b   = (const float*)d_in[14];
  const float* w1      = (const float*)d_in[15];
  const float* b1      = (const float*)d_in[16];
  const float* w2      = (const float*)d_in[17];
  const float* b2      = (const float*)d_in[18];
  float* out = (float*)d_out;

  char* ws = (char*)d_ws;
  size_t cur = 0;
  auto alloc = [&](size_t bytes) -> char* {
    char* p = ws + cur;
    cur += (bytes + 255) & ~(size_t)255;
    return p;
  };
  bf16*  wqkv  = (bf16*) alloc((size_t)NQKVP*256*2);
  bf16*  woutt = (bf16*) alloc((size_t)256*256*2);
  bf16*  w1b   = (bf16*) alloc((size_t)512*256*2);
  bf16*  w2b   = (bf16*) alloc((size_t)256*512*2);
  float* bqkv  = (float*)alloc((size_t)NQKVP*4);
  bf16*  qb    = (bf16*) alloc((size_t)NTOK*256*2);   // live until gemm_ln (residual)
  bf16*  valb  = (bf16*) alloc((size_t)NTOK*256*2);   // [b][g][HW][32]
  float* offv  = (float*)alloc((size_t)NTOK*128*4);
  float* attnl = (float*)alloc((size_t)NTOK*64*4);
  bf16*  aggb  = (bf16*) alloc((size_t)NTOK*256*2);
  bf16*  y1b   = (bf16*) alloc((size_t)NTOK*256*2);

  prep_weights<<<(NQKVP*256 + 256*256 + 512*256 + 256*512 + NQKVP + 255)/256, 256, 0, stream>>>(
      value_W, value_b, off_W, off_b, attn_W, attn_b, out_W, w1, w2,
      wqkv, bqkv, woutt, w1b, w2b);

  qprep_kernel<<<dim3(HW_/64, C_/64, B_), 256, 0, stream>>>(feats, featsp, qb);

  gemm_kernel<0, 256><<<dim3(NTOK/128, NQKVP/128), 256, 0, stream>>>(
      qb, wqkv, bqkv, valb, offv, attnl);

  sample_kernel<<<NTOK/8, 256, 0, stream>>>(valb, offv, attnl, anchors, aggb);

  gemm_ln_kernel<<<NTOK/128, 512, 0, stream>>>(
      aggb, woutt, out_b, qb, ln1_g, ln1_b, y1b);

  ffn_kernel<<<NTOK/128, 512, 0, stream>>>(
      y1b, w1b, b1, w2b, b2, ln2_g, ln2_b, out);
}

// Round 8
// 133.109 us; speedup vs baseline: 2.4179x; 1.0633x over previous
//
#include <hip/hip_runtime.h>
#include <hip/hip_bf16.h>
#include <math.h>
#include <stdint.h>

#define B_ 2
#define C_ 256
#define H_ 80
#define W_ 160
#define HW_ (H_*W_)      // 12800
#define NTOK (B_*HW_)    // 25600
#define G_ 8
#define P_ 8
#define NQKV 448         // 256 val + 128 off + 64 attn (padded to 512 for tiles)
#define NQKVP 512

typedef __bf16 bf16;
typedef __attribute__((ext_vector_type(8))) __bf16 bf16x8;
typedef __attribute__((ext_vector_type(4))) float f32x4;

__device__ __forceinline__ void gload_lds16(const void* g, void* l) {
  __builtin_amdgcn_global_load_lds(
      (__attribute__((address_space(1))) void*)g,
      (__attribute__((address_space(3))) void*)l,
      16, 0, 0);
}

// ---------------- weight prep: transpose to [N][K] bf16, concat+pad qkv -----
__global__ __launch_bounds__(256)
void prep_weights(const float* __restrict__ vW, const float* __restrict__ vb,
                  const float* __restrict__ oW, const float* __restrict__ ob,
                  const float* __restrict__ aW, const float* __restrict__ ab,
                  const float* __restrict__ outW,
                  const float* __restrict__ w1, const float* __restrict__ w2,
                  bf16* __restrict__ wqkv, float* __restrict__ bqkv,
                  bf16* __restrict__ woutt, bf16* __restrict__ w1b, bf16* __restrict__ w2b)
{
  int i = blockIdx.x * 256 + threadIdx.x;
  if (i < NQKVP*256) {                      // wqkv_t[n][k], zero-padded rows
    int nn = i >> 8, k = i & 255;
    float w;
    if (nn < 256)      w = vW[k*256 + nn];
    else if (nn < 384) w = oW[k*128 + (nn-256)];
    else if (nn < 448) w = aW[k*64  + (nn-384)];
    else               w = 0.f;
    wqkv[i] = (bf16)w;
  }
  int j = i - NQKVP*256;
  if (j >= 0 && j < 256*256) {              // outW_t[n][k]
    int nn = j >> 8, k = j & 255;
    woutt[j] = (bf16)outW[k*256 + nn];
  }
  int j2 = i - (NQKVP*256 + 256*256);
  if (j2 >= 0 && j2 < 512*256) w1b[j2] = (bf16)w1[j2];   // already [N][K]
  int j3 = i - (NQKVP*256 + 256*256 + 512*256);
  if (j3 >= 0 && j3 < 256*512) w2b[j3] = (bf16)w2[j3];   // already [N][K]
  int j4 = i - (NQKVP*256 + 256*256 + 512*256 + 256*512);
  if (j4 >= 0 && j4 < NQKVP) {
    float bv;
    if (j4 < 256)      bv = vb[j4];
    else if (j4 < 384) bv = ob[j4-256];
    else if (j4 < 448) bv = ab[j4-384];
    else               bv = 0.f;
    bqkv[j4] = bv;
  }
}

// ---------------- q = (feats+feats_pos) transposed NCHW -> (tok, C) bf16 ----
__global__ __launch_bounds__(256)
void qprep_kernel(const float* __restrict__ f, const float* __restrict__ fp,
                  bf16* __restrict__ qb)
{
  __shared__ float lt[64][65];
  const int tid = threadIdx.x;
  const int n0 = blockIdx.x * 64;   // token tile
  const int c0 = blockIdx.y * 64;   // channel tile
  const int b  = blockIdx.z;
#pragma unroll
  for (int i = 0; i < 16; ++i) {
    int cl = i*4 + (tid >> 6), nl = tid & 63;
    size_t gi = ((size_t)(b*C_ + c0 + cl))*HW_ + n0 + nl;
    lt[cl][nl] = f[gi] + fp[gi];
  }
  __syncthreads();
#pragma unroll
  for (int i = 0; i < 16; ++i) {
    int nl = i*4 + (tid >> 6), cl = tid & 63;
    size_t qi = ((size_t)(b*HW_ + n0 + nl))*C_ + c0 + cl;
    qb[qi] = (bf16)lt[cl][nl];
  }
}

// ---------------- bf16 MFMA GEMM, 128x128 tile, BK=64, XOR-swizzled LDS -----
// EPI 0: qkv  -> val bf16 [b][g][HW][32] / off f32 / attn-logit f32
// EPI 2: ffn1 -> h = bf16(silu(acc+bias))
template<int EPI, int KTOT>
__global__ __launch_bounds__(256)
void gemm_kernel(const bf16* __restrict__ A, const bf16* __restrict__ Bt,
                 const float* __restrict__ bias,
                 void* __restrict__ out0, float* __restrict__ out1,
                 float* __restrict__ out2)
{
  __shared__ bf16 lA[128*64];   // 16 KB, [row][BK] with chunk-XOR swizzle
  __shared__ bf16 lB[128*64];   // 16 KB
  const int tid  = threadIdx.x;
  const int wave = tid >> 6, lane = tid & 63;
  const int m0 = blockIdx.x * 128, n0 = blockIdx.y * 128;
  const int wm = wave >> 1, wn = wave & 1;     // 2x2 wave grid, 64x64 each
  const int fr = lane & 15;
  const int fq = lane >> 4;
  f32x4 acc[4][4] = {};

  for (int kc = 0; kc < KTOT/64; ++kc) {
    if (kc) __syncthreads();
#pragma unroll
    for (int it = 0; it < 4; ++it) {
      int chunk = it*256 + tid;          // 16B-chunk index in 128x64 tile
      int row = chunk >> 3, cb = chunk & 7;
      int ksw = ((cb ^ (row & 7)) << 3); // swizzled k-element offset
      gload_lds16(A  + (size_t)(m0+row)*KTOT + kc*64 + ksw,
                  (char*)lA + it*4096 + wave*1024);
      gload_lds16(Bt + (size_t)(n0+row)*KTOT + kc*64 + ksw,
                  (char*)lB + it*4096 + wave*1024);
    }
    __syncthreads();
#pragma unroll
    for (int ks = 0; ks < 2; ++ks) {
      bf16x8 af[4], bg[4];
#pragma unroll
      for (int i = 0; i < 4; ++i) {
        int ar = wm*64 + i*16 + fr;
        af[i] = *(const bf16x8*)&lA[ar*64 + (((ks*4 + fq) ^ (ar & 7)) << 3)];
        int br = wn*64 + i*16 + fr;
        bg[i] = *(const bf16x8*)&lB[br*64 + (((ks*4 + fq) ^ (br & 7)) << 3)];
      }
#pragma unroll
      for (int mi = 0; mi < 4; ++mi)
#pragma unroll
        for (int ni = 0; ni < 4; ++ni)
          acc[mi][ni] = __builtin_amdgcn_mfma_f32_16x16x32_bf16(af[mi], bg[ni], acc[mi][ni], 0, 0, 0);
    }
  }

#pragma unroll
  for (int mi = 0; mi < 4; ++mi)
#pragma unroll
  for (int ni = 0; ni < 4; ++ni)
#pragma unroll
  for (int r = 0; r < 4; ++r) {
    int row = m0 + wm*64 + mi*16 + fq*4 + r;
    int col = n0 + wn*64 + ni*16 + fr;
    float v = acc[mi][ni][r] + bias[col];
    if (EPI == 0) {
      if (col < 256) {
        // val in [b][g][HW][32] layout for sampling (2 corners per cache line)
        int g = col >> 5, ch = col & 31;
        int b = row >= HW_ ? 1 : 0;
        int n = row - b*HW_;
        ((bf16*)out0)[(((size_t)(b*G_ + g))*HW_ + n)*32 + ch] = (bf16)v;
      }
      else if (col < 384) out1[(size_t)row*128 + (col-256)] = v;
      else if (col < 448) out2[(size_t)row*64  + (col-384)] = v;
      // cols 448..511 are padding: dropped
    } else {
      float s = v / (1.0f + __expf(-v));
      ((bf16*)out0)[(size_t)row*512 + col] = (bf16)s;
    }
  }
}

// ---------------- GEMM (BM=64, BN=256 full row) + residual + LayerNorm ------
// 512 threads = 8 waves in 2(M)x4(N) grid, each 32x64. 400 blocks -> 256 CUs.
// NCHW_OUT=false: y1 = LN1(res + A@Bt^T + bias), bf16 token-major.
// NCHW_OUT=true : out = LN2(res + A@Bt^T + bias), f32 NCHW via LDS retile.
template<int KTOT, bool NCHW_OUT>
__global__ __launch_bounds__(512)
void gemm_ln64_kernel(const bf16* __restrict__ A, const bf16* __restrict__ Bt,
                      const float* __restrict__ bias, const bf16* __restrict__ res,
                      const float* __restrict__ gg, const float* __restrict__ bb,
                      bf16* __restrict__ yb, float* __restrict__ outf)
{
  __shared__ __align__(16) char smem[40960];   // lA 8K | lB 32K ; lt overlay
  bf16* lA = (bf16*)smem;                      // [64][64] swizzled
  bf16* lB = (bf16*)(smem + 8192);             // [256][64] swizzled
  float (*lt)[68] = (float(*)[68])smem;        // 64ch x 64tok retile (17.4K)
  __shared__ float2 red[64][4];                // per-row (sum,sumsq) per wn
  const int tid  = threadIdx.x;
  const int wave = tid >> 6, lane = tid & 63;
  const int m0 = blockIdx.x * 64;
  const int wm = wave >> 2, wn = wave & 3;     // 2x4 wave grid, 32x64 each
  const int fr = lane & 15;
  const int fq = lane >> 4;
  f32x4 acc[2][4] = {};

  for (int kc = 0; kc < KTOT/64; ++kc) {
    if (kc) __syncthreads();
    {                                          // A: 64x64 = 512 chunks, 1/thr
      int row = tid >> 3, cb = tid & 7;
      gload_lds16(A + (size_t)(m0+row)*KTOT + kc*64 + ((cb ^ (row&7))<<3),
                  (char*)lA + wave*1024);
    }
#pragma unroll
    for (int it = 0; it < 4; ++it) {           // B: 256x64 = 2048 chunks
      int chunk = it*512 + tid;
      int row = chunk >> 3, cb = chunk & 7;
      gload_lds16(Bt + (size_t)row*KTOT + kc*64 + ((cb ^ (row&7))<<3),
                  (char*)lB + it*8192 + wave*1024);
    }
    __syncthreads();
#pragma unroll
    for (int ks = 0; ks < 2; ++ks) {
      bf16x8 af[2], bg[4];
#pragma unroll
      for (int i = 0; i < 2; ++i) {
        int ar = wm*32 + i*16 + fr;
        af[i] = *(const bf16x8*)&lA[ar*64 + (((ks*4 + fq) ^ (ar&7))<<3)];
      }
#pragma unroll
      for (int i = 0; i < 4; ++i) {
        int br = wn*64 + i*16 + fr;
        bg[i] = *(const bf16x8*)&lB[br*64 + (((ks*4 + fq) ^ (br&7))<<3)];
      }
#pragma unroll
      for (int mi = 0; mi < 2; ++mi)
#pragma unroll
        for (int ni = 0; ni < 4; ++ni)
          acc[mi][ni] = __builtin_amdgcn_mfma_f32_16x16x32_bf16(af[mi], bg[ni], acc[mi][ni], 0, 0, 0);
    }
  }

  // v = acc + bias + res; per-row LN stats via 16-lane reduce + LDS combine
  float gcol[4], bcol[4];
#pragma unroll
  for (int ni = 0; ni < 4; ++ni) {
    int col = wn*64 + ni*16 + fr;
    gcol[ni] = gg[col]; bcol[ni] = bb[col];
  }
#pragma unroll
  for (int mi = 0; mi < 2; ++mi)
#pragma unroll
  for (int r = 0; r < 4; ++r) {
    int rowl = wm*32 + mi*16 + fq*4 + r;
    size_t rowg = (size_t)(m0 + rowl);
    float s = 0.f, q = 0.f;
#pragma unroll
    for (int ni = 0; ni < 4; ++ni) {
      int col = wn*64 + ni*16 + fr;
      float v = acc[mi][ni][r] + bias[col] + (float)res[rowg*256 + col];
      acc[mi][ni][r] = v;
      s += v; q += v*v;
    }
#pragma unroll
    for (int o = 1; o < 16; o <<= 1) { s += __shfl_xor(s, o, 64); q += __shfl_xor(q, o, 64); }
    if (fr == 0) red[rowl][wn] = make_float2(s, q);
  }
  __syncthreads();
#pragma unroll
  for (int mi = 0; mi < 2; ++mi)
#pragma unroll
  for (int r = 0; r < 4; ++r) {
    int rowl = wm*32 + mi*16 + fq*4 + r;
    float s = 0.f, q = 0.f;
#pragma unroll
    for (int k = 0; k < 4; ++k) { float2 p = red[rowl][k]; s += p.x; q += p.y; }
    const float mean = s * (1.f/256.f);
    const float var  = q * (1.f/256.f) - mean*mean;
    const float rs   = rsqrtf(var + 1e-5f);
#pragma unroll
    for (int ni = 0; ni < 4; ++ni)
      acc[mi][ni][r] = (acc[mi][ni][r] - mean)*rs*gcol[ni] + bcol[ni];
  }

  if constexpr (!NCHW_OUT) {
#pragma unroll
    for (int mi = 0; mi < 2; ++mi)
#pragma unroll
    for (int ni = 0; ni < 4; ++ni)
#pragma unroll
    for (int r = 0; r < 4; ++r) {
      size_t rowg = (size_t)(m0 + wm*32 + mi*16 + fq*4 + r);
      int col = wn*64 + ni*16 + fr;
      yb[rowg*256 + col] = (bf16)acc[mi][ni][r];
    }
  } else {
    // retile through LDS: 4 chunks of 64 channels x 64 tokens, f32 NCHW out
    const int bq = m0 / HW_;
    const int n0 = m0 % HW_;
    __syncthreads();   // lA/lB dead; overlay lt
#pragma unroll
    for (int ch = 0; ch < 4; ++ch) {
      if (ch) __syncthreads();
      if (wn == ch) {
#pragma unroll
        for (int mi = 0; mi < 2; ++mi)
#pragma unroll
        for (int ni = 0; ni < 4; ++ni)
#pragma unroll
        for (int r = 0; r < 4; ++r)
          lt[ni*16 + fr][wm*32 + mi*16 + fq*4 + r] = acc[mi][ni][r];
      }
      __syncthreads();
#pragma unroll
      for (int j = 0; j < 2; ++j) {
        int flat = j*512 + tid;                // 1024 float4 = 64ch x 16
        int cl = flat >> 4, t4 = (flat & 15) * 4;
        float4 v4 = *(const float4*)&lt[cl][t4];
        *(float4*)&outf[((size_t)(bq*C_ + ch*64 + cl))*HW_ + n0 + t4] = v4;
      }
    }
  }
}

// ---------------- softmax + deformable bilinear sampling + aggregate --------
__global__ __launch_bounds__(256)
void sample_kernel(const bf16* __restrict__ val, const float* __restrict__ off,
                   const float* __restrict__ attnl, const float* __restrict__ anchors,
                   bf16* __restrict__ agg)
{
  const int tid  = threadIdx.x;
  const int lane = tid & 63;
  const int wv   = tid >> 6;
  const int c8   = lane & 3;
  const int bid  = blockIdx.x;
  const int g    = bid & 7;
  const int chunk= bid >> 3;
  const int t    = chunk*64 + wv*16 + (lane >> 2);
  const int b    = (t >= HW_) ? 1 : 0;

  const float2 anc = *(const float2*)(anchors + (size_t)t*2);
  const float ax = anc.x * W_ - 0.5f;
  const float ay = anc.y * H_ - 0.5f;

  const float4 l0 = *(const float4*)(attnl + (size_t)t*64 + g*8);
  const float4 l1 = *(const float4*)(attnl + (size_t)t*64 + g*8 + 4);
  float l[8] = {l0.x, l0.y, l0.z, l0.w, l1.x, l1.y, l1.z, l1.w};
  float mx = l[0];
#pragma unroll
  for (int p = 1; p < 8; ++p) mx = fmaxf(mx, l[p]);
  float s = 0.f;
#pragma unroll
  for (int p = 0; p < 8; ++p) { l[p] = __expf(l[p] - mx); s += l[p]; }
  const float inv = 1.f / s;

  const float4* opv = (const float4*)(off + (size_t)t*128 + g*16);
  const float4 o0 = opv[0], o1 = opv[1], o2 = opv[2], o3 = opv[3];
  const float ox[8] = {o0.x, o0.z, o1.x, o1.z, o2.x, o2.z, o3.x, o3.z};
  const float oy[8] = {o0.y, o0.w, o1.y, o1.w, o2.y, o2.w, o3.y, o3.w};

  const bf16* vb = val + ((size_t)(b*G_ + g)*HW_)*32 + c8*8;

  float a[8] = {};
#pragma unroll
  for (int p = 0; p < 8; ++p) {
    const float px = ax + ox[p], py = ay + oy[p];
    const float x0f = floorf(px), y0f = floorf(py);
    const int x0 = (int)x0f, y0 = (int)y0f;
    const float wx1 = px - x0f, wx0 = 1.f - wx1;
    const float wy1 = py - y0f, wy0 = 1.f - wy1;
    const float ap = l[p] * inv;
    float w00 = ap*wx0*wy0, w10 = ap*wx1*wy0, w01 = ap*wx0*wy1, w11 = ap*wx1*wy1;
    const bool vx0 = (unsigned)x0 < W_, vx1 = (unsigned)(x0+1) < W_;
    const bool vy0 = (unsigned)y0 < H_, vy1 = (unsigned)(y0+1) < H_;
    w00 = (vx0 && vy0) ? w00 : 0.f;  w10 = (vx1 && vy0) ? w10 : 0.f;
    w01 = (vx0 && vy1) ? w01 : 0.f;  w11 = (vx1 && vy1) ? w11 : 0.f;
    const int xc0 = min(max(x0, 0), W_-1),   xc1 = min(max(x0+1, 0), W_-1);
    const int yc0 = min(max(y0, 0), H_-1),   yc1 = min(max(y0+1, 0), H_-1);
    const bf16x8 v00 = *(const bf16x8*)(vb + (size_t)(yc0*W_ + xc0)*32);
    const bf16x8 v10 = *(const bf16x8*)(vb + (size_t)(yc0*W_ + xc1)*32);
    const bf16x8 v01 = *(const bf16x8*)(vb + (size_t)(yc1*W_ + xc0)*32);
    const bf16x8 v11 = *(const bf16x8*)(vb + (size_t)(yc1*W_ + xc1)*32);
#pragma unroll
    for (int c = 0; c < 8; ++c)
      a[c] += w00*(float)v00[c] + w10*(float)v10[c]
            + w01*(float)v01[c] + w11*(float)v11[c];
  }
  bf16 r[8];
#pragma unroll
  for (int c = 0; c < 8; ++c) r[c] = (bf16)a[c];
  *(bf16x8*)(agg + (size_t)t*256 + g*32 + c8*8) = *(bf16x8*)r;
}

// ---------------- host-side orchestration -----------------------------------
extern "C" void kernel_launch(void* const* d_in, const int* in_sizes, int n_in,
                              void* d_out, int out_size, void* d_ws, size_t ws_size,
                              hipStream_t stream)
{
  const float* feats   = (const float*)d_in[0];
  const float* featsp  = (const float*)d_in[1];
  const float* anchors = (const float*)d_in[2];
  const float* value_W = (const float*)d_in[3];
  const float* value_b = (const float*)d_in[4];
  const float* off_W   = (const float*)d_in[5];
  const float* off_b   = (const float*)d_in[6];
  const float* attn_W  = (const float*)d_in[7];
  const float* attn_b  = (const float*)d_in[8];
  const float* out_W   = (const float*)d_in[9];
  const float* out_b   = (const float*)d_in[10];
  const float* ln1_g   = (const float*)d_in[11];
  const float* ln1_b   = (const float*)d_in[12];
  const float* ln2_g   = (const float*)d_in[13];
  const float* ln2_b   = (const float*)d_in[14];
  const float* w1      = (const float*)d_in[15];
  const float* b1      = (const float*)d_in[16];
  const float* w2      = (const float*)d_in[17];
  const float* b2      = (const float*)d_in[18];
  float* out = (float*)d_out;

  char* ws = (char*)d_ws;
  size_t cur = 0;
  auto alloc = [&](size_t bytes) -> char* {
    char* p = ws + cur;
    cur += (bytes + 255) & ~(size_t)255;
    return p;
  };
  bf16*  wqkv  = (bf16*) alloc((size_t)NQKVP*256*2);
  bf16*  woutt = (bf16*) alloc((size_t)256*256*2);
  bf16*  w1b   = (bf16*) alloc((size_t)512*256*2);
  bf16*  w2b   = (bf16*) alloc((size_t)256*512*2);
  float* bqkv  = (float*)alloc((size_t)NQKVP*4);
  bf16*  qb    = (bf16*) alloc((size_t)NTOK*256*2);   // live until gemm_ln64 (residual)
  bf16*  valb  = (bf16*) alloc((size_t)NTOK*256*2);   // [b][g][HW][32]
  float* offv  = (float*)alloc((size_t)NTOK*128*4);
  float* attnl = (float*)alloc((size_t)NTOK*64*4);
  bf16*  aggb  = (bf16*) alloc((size_t)NTOK*256*2);
  bf16*  y1b   = (bf16*) alloc((size_t)NTOK*256*2);
  bf16*  hb    = (bf16*) alloc((size_t)NTOK*512*2);

  prep_weights<<<(NQKVP*256 + 256*256 + 512*256 + 256*512 + NQKVP + 255)/256, 256, 0, stream>>>(
      value_W, value_b, off_W, off_b, attn_W, attn_b, out_W, w1, w2,
      wqkv, bqkv, woutt, w1b, w2b);

  qprep_kernel<<<dim3(HW_/64, C_/64, B_), 256, 0, stream>>>(feats, featsp, qb);

  gemm_kernel<0, 256><<<dim3(NTOK/128, NQKVP/128), 256, 0, stream>>>(
      qb, wqkv, bqkv, valb, offv, attnl);

  sample_kernel<<<NTOK/8, 256, 0, stream>>>(valb, offv, attnl, anchors, aggb);

  gemm_ln64_kernel<256, false><<<NTOK/64, 512, 0, stream>>>(
      aggb, woutt, out_b, qb, ln1_g, ln1_b, y1b, nullptr);

  gemm_kernel<2, 256><<<dim3(NTOK/128, 512/128), 256, 0, stream>>>(
      y1b, w1b, b1, hb, nullptr, nullptr);

  gemm_ln64_kernel<512, true><<<NTOK/64, 512, 0, stream>>>(
      hb, w2b, b2, y1b, ln2_g, ln2_b, nullptr, out);
}

// Round 9
// 131.837 us; speedup vs baseline: 2.4412x; 1.0096x over previous
//
#include <hip/hip_runtime.h>
#include <hip/hip_bf16.h>
#include <math.h>
#include <stdint.h>

#define B_ 2
#define C_ 256
#define H_ 80
#define W_ 160
#define HW_ (H_*W_)      // 12800
#define NTOK (B_*HW_)    // 25600
#define G_ 8
#define P_ 8
#define NQKV 448         // 256 val + 128 off + 64 attn (padded to 512 for tiles)
#define NQKVP 512
#define PREP_BLOCKS 1794 // (NQKVP*256+256*256+512*256+256*512+NQKVP)/256

typedef __bf16 bf16;
typedef __attribute__((ext_vector_type(8))) __bf16 bf16x8;
typedef __attribute__((ext_vector_type(4))) float f32x4;

__device__ __forceinline__ void gload_lds16(const void* g, void* l) {
  __builtin_amdgcn_global_load_lds(
      (__attribute__((address_space(1))) void*)g,
      (__attribute__((address_space(3))) void*)l,
      16, 0, 0);
}

// ------- merged prep: weight transpose/cast + q = transpose(f+fp) bf16 ------
__global__ __launch_bounds__(256)
void prep_kernel(const float* __restrict__ vW, const float* __restrict__ vb,
                 const float* __restrict__ oW, const float* __restrict__ ob,
                 const float* __restrict__ aW, const float* __restrict__ ab,
                 const float* __restrict__ outW,
                 const float* __restrict__ w1, const float* __restrict__ w2,
                 const float* __restrict__ f, const float* __restrict__ fp,
                 bf16* __restrict__ wqkv, float* __restrict__ bqkv,
                 bf16* __restrict__ woutt, bf16* __restrict__ w1b,
                 bf16* __restrict__ w2b, bf16* __restrict__ qb)
{
  __shared__ float lt[64][65];
  const int tid = threadIdx.x;
  const int bid = blockIdx.x;
  if (bid < PREP_BLOCKS) {
    int i = bid * 256 + tid;
    if (i < NQKVP*256) {                      // wqkv_t[n][k], zero-padded rows
      int nn = i >> 8, k = i & 255;
      float w;
      if (nn < 256)      w = vW[k*256 + nn];
      else if (nn < 384) w = oW[k*128 + (nn-256)];
      else if (nn < 448) w = aW[k*64  + (nn-384)];
      else               w = 0.f;
      wqkv[i] = (bf16)w;
    }
    int j = i - NQKVP*256;
    if (j >= 0 && j < 256*256) {              // outW_t[n][k]
      int nn = j >> 8, k = j & 255;
      woutt[j] = (bf16)outW[k*256 + nn];
    }
    int j2 = i - (NQKVP*256 + 256*256);
    if (j2 >= 0 && j2 < 512*256) w1b[j2] = (bf16)w1[j2];   // already [N][K]
    int j3 = i - (NQKVP*256 + 256*256 + 512*256);
    if (j3 >= 0 && j3 < 256*512) w2b[j3] = (bf16)w2[j3];   // already [N][K]
    int j4 = i - (NQKVP*256 + 256*256 + 512*256 + 256*512);
    if (j4 >= 0 && j4 < NQKVP) {
      float bv;
      if (j4 < 256)      bv = vb[j4];
      else if (j4 < 384) bv = ob[j4-256];
      else if (j4 < 448) bv = ab[j4-384];
      else               bv = 0.f;
      bqkv[j4] = bv;
    }
  } else {
    const int b2 = bid - PREP_BLOCKS;
    const int n0 = (b2 % 200) * 64;
    const int c0 = ((b2 / 200) & 3) * 64;
    const int b  = b2 / 800;
#pragma unroll
    for (int i = 0; i < 16; ++i) {
      int cl = i*4 + (tid >> 6), nl = tid & 63;
      size_t gi = ((size_t)(b*C_ + c0 + cl))*HW_ + n0 + nl;
      lt[cl][nl] = f[gi] + fp[gi];
    }
    __syncthreads();
#pragma unroll
    for (int i = 0; i < 16; ++i) {
      int nl = i*4 + (tid >> 6), cl = tid & 63;
      size_t qi = ((size_t)(b*HW_ + n0 + nl))*C_ + c0 + cl;
      qb[qi] = (bf16)lt[cl][nl];
    }
  }
}

// ---------------- bf16 MFMA GEMM, 128x128 tile, BK=64, XOR-swizzled LDS -----
// EPI 0: qkv  -> val bf16 [b][g][HW][32] / off f32 / attn-logit f32
// EPI 2: ffn1 -> h = bf16(silu(acc+bias))
template<int EPI, int KTOT>
__global__ __launch_bounds__(256)
void gemm_kernel(const bf16* __restrict__ A, const bf16* __restrict__ Bt,
                 const float* __restrict__ bias,
                 void* __restrict__ out0, float* __restrict__ out1,
                 float* __restrict__ out2)
{
  __shared__ bf16 lA[128*64];   // 16 KB, [row][BK] with chunk-XOR swizzle
  __shared__ bf16 lB[128*64];   // 16 KB
  const int tid  = threadIdx.x;
  const int wave = tid >> 6, lane = tid & 63;
  const int m0 = blockIdx.x * 128, n0 = blockIdx.y * 128;
  const int wm = wave >> 1, wn = wave & 1;     // 2x2 wave grid, 64x64 each
  const int fr = lane & 15;
  const int fq = lane >> 4;
  f32x4 acc[4][4] = {};

  for (int kc = 0; kc < KTOT/64; ++kc) {
    if (kc) __syncthreads();
#pragma unroll
    for (int it = 0; it < 4; ++it) {
      int chunk = it*256 + tid;          // 16B-chunk index in 128x64 tile
      int row = chunk >> 3, cb = chunk & 7;
      int ksw = ((cb ^ (row & 7)) << 3); // swizzled k-element offset
      gload_lds16(A  + (size_t)(m0+row)*KTOT + kc*64 + ksw,
                  (char*)lA + it*4096 + wave*1024);
      gload_lds16(Bt + (size_t)(n0+row)*KTOT + kc*64 + ksw,
                  (char*)lB + it*4096 + wave*1024);
    }
    __syncthreads();
#pragma unroll
    for (int ks = 0; ks < 2; ++ks) {
      bf16x8 af[4], bg[4];
#pragma unroll
      for (int i = 0; i < 4; ++i) {
        int ar = wm*64 + i*16 + fr;
        af[i] = *(const bf16x8*)&lA[ar*64 + (((ks*4 + fq) ^ (ar & 7)) << 3)];
        int br = wn*64 + i*16 + fr;
        bg[i] = *(const bf16x8*)&lB[br*64 + (((ks*4 + fq) ^ (br & 7)) << 3)];
      }
#pragma unroll
      for (int mi = 0; mi < 4; ++mi)
#pragma unroll
        for (int ni = 0; ni < 4; ++ni)
          acc[mi][ni] = __builtin_amdgcn_mfma_f32_16x16x32_bf16(af[mi], bg[ni], acc[mi][ni], 0, 0, 0);
    }
  }

#pragma unroll
  for (int mi = 0; mi < 4; ++mi)
#pragma unroll
  for (int ni = 0; ni < 4; ++ni)
#pragma unroll
  for (int r = 0; r < 4; ++r) {
    int row = m0 + wm*64 + mi*16 + fq*4 + r;
    int col = n0 + wn*64 + ni*16 + fr;
    float v = acc[mi][ni][r] + bias[col];
    if (EPI == 0) {
      if (col < 256) {
        // val in [b][g][HW][32] layout for sampling (2 corners per cache line)
        int g = col >> 5, ch = col & 31;
        int b = row >= HW_ ? 1 : 0;
        int n = row - b*HW_;
        ((bf16*)out0)[(((size_t)(b*G_ + g))*HW_ + n)*32 + ch] = (bf16)v;
      }
      else if (col < 384) out1[(size_t)row*128 + (col-256)] = v;
      else if (col < 448) out2[(size_t)row*64  + (col-384)] = v;
      // cols 448..511 are padding: dropped
    } else {
      float s = v / (1.0f + __expf(-v));
      ((bf16*)out0)[(size_t)row*512 + col] = (bf16)s;
    }
  }
}

// ---------------- GEMM (BM=64, BN=256 full row) + residual + LayerNorm ------
// 512 threads = 8 waves in 2(M)x4(N) grid, each 32x64. 400 blocks -> 256 CUs.
// NCHW_OUT=false: y1 = LN1(res + A@Bt^T + bias), bf16 token-major.
// NCHW_OUT=true : out = LN2(res + A@Bt^T + bias), f32 NCHW via LDS retile.
template<int KTOT, bool NCHW_OUT>
__global__ __launch_bounds__(512)
void gemm_ln64_kernel(const bf16* __restrict__ A, const bf16* __restrict__ Bt,
                      const float* __restrict__ bias, const bf16* __restrict__ res,
                      const float* __restrict__ gg, const float* __restrict__ bb,
                      bf16* __restrict__ yb, float* __restrict__ outf)
{
  __shared__ __align__(16) char smem[40960];   // lA 8K | lB 32K ; lt overlay
  bf16* lA = (bf16*)smem;                      // [64][64] swizzled
  bf16* lB = (bf16*)(smem + 8192);             // [256][64] swizzled
  float (*lt)[68] = (float(*)[68])smem;        // 64ch x 64tok retile (17.4K)
  __shared__ float2 red[64][4];                // per-row (sum,sumsq) per wn
  const int tid  = threadIdx.x;
  const int wave = tid >> 6, lane = tid & 63;
  const int m0 = blockIdx.x * 64;
  const int wm = wave >> 2, wn = wave & 3;     // 2x4 wave grid, 32x64 each
  const int fr = lane & 15;
  const int fq = lane >> 4;
  f32x4 acc[2][4] = {};

  for (int kc = 0; kc < KTOT/64; ++kc) {
    if (kc) __syncthreads();
    {                                          // A: 64x64 = 512 chunks, 1/thr
      int row = tid >> 3, cb = tid & 7;
      gload_lds16(A + (size_t)(m0+row)*KTOT + kc*64 + ((cb ^ (row&7))<<3),
                  (char*)lA + wave*1024);
    }
#pragma unroll
    for (int it = 0; it < 4; ++it) {           // B: 256x64 = 2048 chunks
      int chunk = it*512 + tid;
      int row = chunk >> 3, cb = chunk & 7;
      gload_lds16(Bt + (size_t)row*KTOT + kc*64 + ((cb ^ (row&7))<<3),
                  (char*)lB + it*8192 + wave*1024);
    }
    __syncthreads();
#pragma unroll
    for (int ks = 0; ks < 2; ++ks) {
      bf16x8 af[2], bg[4];
#pragma unroll
      for (int i = 0; i < 2; ++i) {
        int ar = wm*32 + i*16 + fr;
        af[i] = *(const bf16x8*)&lA[ar*64 + (((ks*4 + fq) ^ (ar&7))<<3)];
      }
#pragma unroll
      for (int i = 0; i < 4; ++i) {
        int br = wn*64 + i*16 + fr;
        bg[i] = *(const bf16x8*)&lB[br*64 + (((ks*4 + fq) ^ (br&7))<<3)];
      }
#pragma unroll
      for (int mi = 0; mi < 2; ++mi)
#pragma unroll
        for (int ni = 0; ni < 4; ++ni)
          acc[mi][ni] = __builtin_amdgcn_mfma_f32_16x16x32_bf16(af[mi], bg[ni], acc[mi][ni], 0, 0, 0);
    }
  }

  // v = acc + bias + res; per-row LN stats via 16-lane reduce + LDS combine
  float gcol[4], bcol[4];
#pragma unroll
  for (int ni = 0; ni < 4; ++ni) {
    int col = wn*64 + ni*16 + fr;
    gcol[ni] = gg[col]; bcol[ni] = bb[col];
  }
#pragma unroll
  for (int mi = 0; mi < 2; ++mi)
#pragma unroll
  for (int r = 0; r < 4; ++r) {
    int rowl = wm*32 + mi*16 + fq*4 + r;
    size_t rowg = (size_t)(m0 + rowl);
    float s = 0.f, q = 0.f;
#pragma unroll
    for (int ni = 0; ni < 4; ++ni) {
      int col = wn*64 + ni*16 + fr;
      float v = acc[mi][ni][r] + bias[col] + (float)res[rowg*256 + col];
      acc[mi][ni][r] = v;
      s += v; q += v*v;
    }
#pragma unroll
    for (int o = 1; o < 16; o <<= 1) { s += __shfl_xor(s, o, 64); q += __shfl_xor(q, o, 64); }
    if (fr == 0) red[rowl][wn] = make_float2(s, q);
  }
  __syncthreads();
#pragma unroll
  for (int mi = 0; mi < 2; ++mi)
#pragma unroll
  for (int r = 0; r < 4; ++r) {
    int rowl = wm*32 + mi*16 + fq*4 + r;
    float s = 0.f, q = 0.f;
#pragma unroll
    for (int k = 0; k < 4; ++k) { float2 p = red[rowl][k]; s += p.x; q += p.y; }
    const float mean = s * (1.f/256.f);
    const float var  = q * (1.f/256.f) - mean*mean;
    const float rs   = rsqrtf(var + 1e-5f);
#pragma unroll
    for (int ni = 0; ni < 4; ++ni)
      acc[mi][ni][r] = (acc[mi][ni][r] - mean)*rs*gcol[ni] + bcol[ni];
  }

  if constexpr (!NCHW_OUT) {
#pragma unroll
    for (int mi = 0; mi < 2; ++mi)
#pragma unroll
    for (int ni = 0; ni < 4; ++ni)
#pragma unroll
    for (int r = 0; r < 4; ++r) {
      size_t rowg = (size_t)(m0 + wm*32 + mi*16 + fq*4 + r);
      int col = wn*64 + ni*16 + fr;
      yb[rowg*256 + col] = (bf16)acc[mi][ni][r];
    }
  } else {
    // retile through LDS: 4 chunks of 64 channels x 64 tokens, f32 NCHW out
    const int bq = m0 / HW_;
    const int n0 = m0 % HW_;
    __syncthreads();   // lA/lB dead; overlay lt
#pragma unroll
    for (int ch = 0; ch < 4; ++ch) {
      if (ch) __syncthreads();
      if (wn == ch) {
#pragma unroll
        for (int mi = 0; mi < 2; ++mi)
#pragma unroll
        for (int ni = 0; ni < 4; ++ni)
#pragma unroll
        for (int r = 0; r < 4; ++r)
          lt[ni*16 + fr][wm*32 + mi*16 + fq*4 + r] = acc[mi][ni][r];
      }
      __syncthreads();
#pragma unroll
      for (int j = 0; j < 2; ++j) {
        int flat = j*512 + tid;                // 1024 float4 = 64ch x 16
        int cl = flat >> 4, t4 = (flat & 15) * 4;
        float4 v4 = *(const float4*)&lt[cl][t4];
        *(float4*)&outf[((size_t)(bq*C_ + ch*64 + cl))*HW_ + n0 + t4] = v4;
      }
    }
  }
}

// ---------------- softmax + deformable bilinear sampling + aggregate --------
// Group-partitioned blocks (g = bid%8 -> XCD); lane = (tok:4)(c8:2).
// 4-point batches: 16 weights+offsets computed, then 16 gathers in flight,
// then the FMA block — static indices keep everything in registers.
__global__ __launch_bounds__(256)
void sample_kernel(const bf16* __restrict__ val, const float* __restrict__ off,
                   const float* __restrict__ attnl, const float* __restrict__ anchors,
                   bf16* __restrict__ agg)
{
  const int tid  = threadIdx.x;
  const int lane = tid & 63;
  const int wv   = tid >> 6;
  const int c8   = lane & 3;
  const int bid  = blockIdx.x;
  const int g    = bid & 7;
  const int chunk= bid >> 3;
  const int t    = chunk*64 + wv*16 + (lane >> 2);
  const int b    = (t >= HW_) ? 1 : 0;

  const float2 anc = *(const float2*)(anchors + (size_t)t*2);
  const float ax = anc.x * W_ - 0.5f;
  const float ay = anc.y * H_ - 0.5f;

  const float4 l0 = *(const float4*)(attnl + (size_t)t*64 + g*8);
  const float4 l1 = *(const float4*)(attnl + (size_t)t*64 + g*8 + 4);
  float l[8] = {l0.x, l0.y, l0.z, l0.w, l1.x, l1.y, l1.z, l1.w};
  float mx = l[0];
#pragma unroll
  for (int p = 1; p < 8; ++p) mx = fmaxf(mx, l[p]);
  float s = 0.f;
#pragma unroll
  for (int p = 0; p < 8; ++p) { l[p] = __expf(l[p] - mx); s += l[p]; }
  const float inv = 1.f / s;

  const float4* opv = (const float4*)(off + (size_t)t*128 + g*16);
  const float4 o0 = opv[0], o1 = opv[1], o2 = opv[2], o3 = opv[3];
  const float ox[8] = {o0.x, o0.z, o1.x, o1.z, o2.x, o2.z, o3.x, o3.z};
  const float oy[8] = {o0.y, o0.w, o1.y, o1.w, o2.y, o2.w, o3.y, o3.w};

  const bf16* vb = val + ((size_t)(b*G_ + g)*HW_)*32 + c8*8;

  float a[8] = {};
#pragma unroll
  for (int pb = 0; pb < 2; ++pb) {
    float w4[4][4];
    int   ofs[4][4];
#pragma unroll
    for (int pi = 0; pi < 4; ++pi) {
      const int p = pb*4 + pi;
      const float px = ax + ox[p], py = ay + oy[p];
      const float x0f = floorf(px), y0f = floorf(py);
      const int x0 = (int)x0f, y0 = (int)y0f;
      const float wx1 = px - x0f, wx0 = 1.f - wx1;
      const float wy1 = py - y0f, wy0 = 1.f - wy1;
      const float ap = l[p] * inv;
      const bool vx0 = (unsigned)x0 < W_, vx1 = (unsigned)(x0+1) < W_;
      const bool vy0 = (unsigned)y0 < H_, vy1 = (unsigned)(y0+1) < H_;
      w4[pi][0] = (vx0 && vy0) ? ap*wx0*wy0 : 0.f;
      w4[pi][1] = (vx1 && vy0) ? ap*wx1*wy0 : 0.f;
      w4[pi][2] = (vx0 && vy1) ? ap*wx0*wy1 : 0.f;
      w4[pi][3] = (vx1 && vy1) ? ap*wx1*wy1 : 0.f;
      const int xc0 = min(max(x0, 0), W_-1),   xc1 = min(max(x0+1, 0), W_-1);
      const int yc0 = min(max(y0, 0), H_-1),   yc1 = min(max(y0+1, 0), H_-1);
      ofs[pi][0] = (yc0*W_ + xc0)*32;
      ofs[pi][1] = (yc0*W_ + xc1)*32;
      ofs[pi][2] = (yc1*W_ + xc0)*32;
      ofs[pi][3] = (yc1*W_ + xc1)*32;
    }
    bf16x8 v[4][4];
#pragma unroll
    for (int pi = 0; pi < 4; ++pi)
#pragma unroll
      for (int cn = 0; cn < 4; ++cn)
        v[pi][cn] = *(const bf16x8*)(vb + ofs[pi][cn]);
#pragma unroll
    for (int pi = 0; pi < 4; ++pi)
#pragma unroll
      for (int cn = 0; cn < 4; ++cn)
#pragma unroll
        for (int c = 0; c < 8; ++c)
          a[c] += w4[pi][cn] * (float)v[pi][cn][c];
  }
  bf16 r[8];
#pragma unroll
  for (int c = 0; c < 8; ++c) r[c] = (bf16)a[c];
  *(bf16x8*)(agg + (size_t)t*256 + g*32 + c8*8) = *(bf16x8*)r;
}

// ---------------- host-side orchestration -----------------------------------
extern "C" void kernel_launch(void* const* d_in, const int* in_sizes, int n_in,
                              void* d_out, int out_size, void* d_ws, size_t ws_size,
                              hipStream_t stream)
{
  const float* feats   = (const float*)d_in[0];
  const float* featsp  = (const float*)d_in[1];
  const float* anchors = (const float*)d_in[2];
  const float* value_W = (const float*)d_in[3];
  const float* value_b = (const float*)d_in[4];
  const float* off_W   = (const float*)d_in[5];
  const float* off_b   = (const float*)d_in[6];
  const float* attn_W  = (const float*)d_in[7];
  const float* attn_b  = (const float*)d_in[8];
  const float* out_W   = (const float*)d_in[9];
  const float* out_b   = (const float*)d_in[10];
  const float* ln1_g   = (const float*)d_in[11];
  const float* ln1_b   = (const float*)d_in[12];
  const float* ln2_g   = (const float*)d_in[13];
  const float* ln2_b   = (const float*)d_in[14];
  const float* w1      = (const float*)d_in[15];
  const float* b1      = (const float*)d_in[16];
  const float* w2      = (const float*)d_in[17];
  const float* b2      = (const float*)d_in[18];
  float* out = (float*)d_out;

  char* ws = (char*)d_ws;
  size_t cur = 0;
  auto alloc = [&](size_t bytes) -> char* {
    char* p = ws + cur;
    cur += (bytes + 255) & ~(size_t)255;
    return p;
  };
  bf16*  wqkv  = (bf16*) alloc((size_t)NQKVP*256*2);
  bf16*  woutt = (bf16*) alloc((size_t)256*256*2);
  bf16*  w1b   = (bf16*) alloc((size_t)512*256*2);
  bf16*  w2b   = (bf16*) alloc((size_t)256*512*2);
  float* bqkv  = (float*)alloc((size_t)NQKVP*4);
  bf16*  qb    = (bf16*) alloc((size_t)NTOK*256*2);   // live until gemm_ln64 (residual)
  bf16*  valb  = (bf16*) alloc((size_t)NTOK*256*2);   // [b][g][HW][32]
  float* offv  = (float*)alloc((size_t)NTOK*128*4);
  float* attnl = (float*)alloc((size_t)NTOK*64*4);
  bf16*  aggb  = (bf16*) alloc((size_t)NTOK*256*2);
  bf16*  y1b   = (bf16*) alloc((size_t)NTOK*256*2);
  bf16*  hb    = (bf16*) alloc((size_t)NTOK*512*2);

  prep_kernel<<<PREP_BLOCKS + 1600, 256, 0, stream>>>(
      value_W, value_b, off_W, off_b, attn_W, attn_b, out_W, w1, w2,
      feats, featsp, wqkv, bqkv, woutt, w1b, w2b, qb);

  gemm_kernel<0, 256><<<dim3(NTOK/128, NQKVP/128), 256, 0, stream>>>(
      qb, wqkv, bqkv, valb, offv, attnl);

  sample_kernel<<<NTOK/8, 256, 0, stream>>>(valb, offv, attnl, anchors, aggb);

  gemm_ln64_kernel<256, false><<<NTOK/64, 512, 0, stream>>>(
      aggb, woutt, out_b, qb, ln1_g, ln1_b, y1b, nullptr);

  gemm_kernel<2, 256><<<dim3(NTOK/128, 512/128), 256, 0, stream>>>(
      y1b, w1b, b1, hb, nullptr, nullptr);

  gemm_ln64_kernel<512, true><<<NTOK/64, 512, 0, stream>>>(
      hb, w2b, b2, y1b, ln2_g, ln2_b, nullptr, out);
}